// Round 7
// baseline (392.361 us; speedup 1.0000x reference)
//
#include <hip/hip_runtime.h>
#include <hip/hip_bf16.h>

typedef float f32x4 __attribute__((ext_vector_type(4)));
typedef float f32x2 __attribute__((ext_vector_type(2)));
typedef short s16x8 __attribute__((ext_vector_type(8)));
typedef short s16x4 __attribute__((ext_vector_type(4)));

#define NB  4
#define NTQ 128
#define NTK 512
#define NH  1024
#define GRID_BLKS 512

__device__ __forceinline__ unsigned short f2bf(float x) {
    unsigned u = __builtin_bit_cast(unsigned, x);
    u += 0x7FFFu + ((u >> 16) & 1u);          // round-to-nearest-even
    return (unsigned short)(u >> 16);
}

#define K2E  2.8853900817779268f   // 2*log2(e): exp2(K2E*x) = e^{2x}

// async global->LDS 16B: linear LDS dest (wave base + lane*16), per-lane global src
#define GLD16(gp, lp) __builtin_amdgcn_global_load_lds( \
    (const __attribute__((address_space(1))) unsigned int*)(gp), \
    (__attribute__((address_space(3))) unsigned int*)(lp), 16, 0, 0)

// device-scope multi-use-free grid barrier: one {count,flag} pair per barrier idx.
// All blocks resident by construction (launch_bounds + 48KB LDS -> 2 blocks/CU, grid=512).
__device__ __forceinline__ void grid_barrier(unsigned* bar, int idx, unsigned nblk) {
    __syncthreads();
    if (threadIdx.x == 0) {
        __threadfence();                                   // release: drain + L2 writeback
        unsigned* cnt = bar + idx * 2;
        unsigned* flg = cnt + 1;
        unsigned t = __hip_atomic_fetch_add(cnt, 1u, __ATOMIC_ACQ_REL,
                                            __HIP_MEMORY_SCOPE_AGENT);
        if (t == nblk - 1u) {
            __hip_atomic_store(flg, 1u, __ATOMIC_RELEASE, __HIP_MEMORY_SCOPE_AGENT);
        } else {
            while (__hip_atomic_load(flg, __ATOMIC_ACQUIRE,
                                     __HIP_MEMORY_SCOPE_AGENT) == 0u)
                __builtin_amdgcn_s_sleep(2);
        }
        __threadfence();                                   // acquire: invalidate L1/L2
    }
    __syncthreads();
}

__global__ __launch_bounds__(512, 4) void mega_kernel(
    const float* __restrict__ Q, const float* __restrict__ Kmat,
    const float* __restrict__ value,
    const float* __restrict__ Wq, const float* __restrict__ bq,
    const float* __restrict__ Wk, const float* __restrict__ vvec,
    short* __restrict__ Qb, short* __restrict__ Kb,
    short* __restrict__ WqT, short* __restrict__ WkT, short* __restrict__ valT,
    float* __restrict__ Ea, float* __restrict__ EbT,
    float* __restrict__ part, float* __restrict__ attn_out,
    short* __restrict__ attnb, float* __restrict__ outh,
    unsigned* __restrict__ bar)
{
    __shared__ __align__(16) char smem[49152];
    const int T = threadIdx.x, BID = blockIdx.x;
    const unsigned NBLK = gridDim.x;
    const int lane = T & 63, wid = T >> 6;
    const int wr = wid >> 2, wc = wid & 3;              // 8 waves: 2m x 4n
    const int fr = lane & 15, fko = (lane >> 4) * 16;   // frag row, byte k-offset
    const int row0 = (lane >> 4) * 4;                   // C/D row base

    // ================= stage 1: prep (bf16 convert + transposes) ==============
    {
        // (a) straight copies Q,K -> bf16 (float4-granular grid-stride)
        for (int i = BID * 512 + T; i < 655360; i += GRID_BLKS * 512) {
            const size_t off = (size_t)i * 4;
            const float* src; short* dst; size_t o;
            if (off < 524288) { src = Q;    dst = Qb; o = off; }
            else              { src = Kmat; dst = Kb; o = off - 524288; }
            const float4 vv = *(const float4*)(src + o);
            s16x4 ov = { (short)f2bf(vv.x), (short)f2bf(vv.y),
                         (short)f2bf(vv.z), (short)f2bf(vv.w) };
            *(s16x4*)(dst + o) = ov;
        }
        // (b) 64x64 transpose-convert tiles: Wq(256) | Wk(256) | value(512)
        float (*tr)[64][65] = (float(*)[64][65])smem;
        const int tsel = T >> 8, t8 = T & 255;
        const int tv = BID * 2 + tsel;                 // 0..1023
        const float* src; short* dst; int Cs, Rs, r0, c0;
        if (tv < 256)      { src = Wq; dst = WqT; Cs = 1024; Rs = 1024; r0 = (tv >> 4) * 64; c0 = (tv & 15) * 64; }
        else if (tv < 512) { const int j = tv - 256; src = Wk; dst = WkT; Cs = 1024; Rs = 1024; r0 = (j >> 4) * 64; c0 = (j & 15) * 64; }
        else {
            const int j = tv - 512, b = j >> 7, ti = j & 127;
            src = value + (size_t)b * 512 * 1024; dst = valT + (size_t)b * 1024 * 512;
            Cs = 1024; Rs = 512; r0 = (ti >> 4) * 64; c0 = (ti & 15) * 64;
        }
        {
            const int c = (t8 & 15) * 4;
            #pragma unroll
            for (int it = 0; it < 4; ++it) {
                const int r = (t8 >> 4) + it * 16;
                const float4 vv = *(const float4*)(src + (size_t)(r0 + r) * Cs + c0 + c);
                tr[tsel][r][c + 0] = vv.x; tr[tsel][r][c + 1] = vv.y;
                tr[tsel][r][c + 2] = vv.z; tr[tsel][r][c + 3] = vv.w;
            }
        }
        __syncthreads();
        {
            const int r = (t8 & 15) * 4;
            #pragma unroll
            for (int it = 0; it < 4; ++it) {
                const int c = (t8 >> 4) + it * 16;
                s16x4 ov = { (short)f2bf(tr[tsel][r + 0][c]), (short)f2bf(tr[tsel][r + 1][c]),
                             (short)f2bf(tr[tsel][r + 2][c]), (short)f2bf(tr[tsel][r + 3][c]) };
                *(s16x4*)(dst + (size_t)(c0 + c) * Rs + r0 + r) = ov;
            }
        }
    }
    grid_barrier(bar, 0, NBLK);

    // ================= stage 2: mm (Ea, EbT), 320 virtual tiles ==============
    if (BID < 320) {
        const int bx = (BID & 7) * 40 + (BID >> 3);    // XCD-chunked swizzle
        const bool g1 = bx < 64;
        const short *A, *B; int m0, n0;
        if (g1) { A = Qb; B = WqT; m0 = (bx >> 4) * 128; n0 = (bx & 15) * 64; }
        else    { const int i = bx - 64; A = Kb; B = WkT; m0 = (i >> 4) * 128; n0 = (i & 15) * 64; }
        A += (size_t)m0 * 1024; B += (size_t)n0 * 1024;

        short* lA = (short*)smem;                       // [2][128][64]
        short* lB = (short*)(smem + 32768);             // [2][64][64]
        f32x4 acc[4];
        #pragma unroll
        for (int i = 0; i < 4; ++i) acc[i] = f32x4{0.f, 0.f, 0.f, 0.f};

        #define MM_STAGE(buf, k0) do {                                          \
            _Pragma("unroll")                                                   \
            for (int it = 0; it < 2; ++it) {                                    \
                const int idx = it * 512 + T;                                   \
                const int row = idx >> 3, c16 = idx & 7;                        \
                const int sc = c16 ^ (row & 7);                                 \
                GLD16(A + (size_t)row * 1024 + (k0) + sc * 8,                   \
                      lA + (buf) * 8192 + idx * 8);                             \
            }                                                                   \
            {                                                                   \
                const int idx = T;                                              \
                const int row = idx >> 3, c16 = idx & 7;                        \
                const int sc = c16 ^ (row & 7);                                 \
                GLD16(B + (size_t)row * 1024 + (k0) + sc * 8,                   \
                      lB + (buf) * 4096 + idx * 8);                             \
            }                                                                   \
        } while (0)

        #define MM_COMP(buf) do {                                               \
            _Pragma("unroll")                                                   \
            for (int kk = 0; kk < 2; ++kk) {                                    \
                s16x8 af[4], bf1;                                               \
                _Pragma("unroll")                                               \
                for (int i = 0; i < 4; ++i) {                                   \
                    const int rowA = wr * 64 + i * 16 + fr;                     \
                    int offA = rowA * 128 + kk * 64 + fko; offA ^= (rowA & 7) << 4; \
                    af[i] = *(const s16x8*)((const char*)(lA + (buf) * 8192) + offA); \
                }                                                               \
                {                                                               \
                    const int rowB = wc * 16 + fr;                              \
                    int offB = rowB * 128 + kk * 64 + fko; offB ^= (rowB & 7) << 4; \
                    bf1 = *(const s16x8*)((const char*)(lB + (buf) * 4096) + offB); \
                }                                                               \
                _Pragma("unroll")                                               \
                for (int mi = 0; mi < 4; ++mi)                                  \
                    acc[mi] = __builtin_amdgcn_mfma_f32_16x16x32_bf16(          \
                                  af[mi], bf1, acc[mi], 0, 0, 0);               \
            }                                                                   \
        } while (0)

        MM_STAGE(0, 0);
        __syncthreads();
        int cur = 0;
        for (int s = 0; s < 15; ++s) {
            MM_STAGE(cur ^ 1, (s + 1) * 64);
            MM_COMP(cur);
            __syncthreads();
            cur ^= 1;
        }
        MM_COMP(cur);

        const int n = n0 + wc * 16 + fr;
        if (g1) {
            const float bias = bq[n];
            #pragma unroll
            for (int mi = 0; mi < 4; ++mi) {
                const int m = m0 + wr * 64 + mi * 16 + row0;
                #pragma unroll
                for (int j = 0; j < 4; ++j)
                    Ea[(size_t)(m + j) * 1024 + n] =
                        __builtin_amdgcn_exp2f(K2E * (acc[mi][j] + bias));
            }
        } else {
            #pragma unroll
            for (int mi = 0; mi < 4; ++mi) {
                const int m = m0 + wr * 64 + mi * 16 + row0;
                const int b = m >> 9, kx = m & 511;
                f32x4 ev;
                #pragma unroll
                for (int j = 0; j < 4; ++j)
                    ev[j] = __builtin_amdgcn_exp2f(K2E * acc[mi][j]);
                *(f32x4*)&EbT[((size_t)b * 1024 + n) * 512 + kx] = ev;
            }
        }
        #undef MM_STAGE
        #undef MM_COMP
    }
    grid_barrier(bar, 1, NBLK);

    // ================= stage 3: scores partials (1024 virtual blocks) =========
    {
        float4 (*sea)[2] = (float4(*)[2])smem;          // [64][2]
        float* sv = (float*)(smem + 2048);              // [64]
        for (int rep = 0; rep < 2; ++rep) {
            const int bx = BID * 2 + rep;
            const int hc = bx & 15, bq8 = bx >> 4;
            const int b = bq8 >> 4, q8 = bq8 & 15;
            const int bq0 = b * 128 + q8 * 8, h0 = hc * 64;
            __syncthreads();
            if (T < 64) {
                const int h = h0 + T;
                sea[T][0] = make_float4(Ea[(size_t)(bq0 + 0) * 1024 + h],
                                        Ea[(size_t)(bq0 + 1) * 1024 + h],
                                        Ea[(size_t)(bq0 + 2) * 1024 + h],
                                        Ea[(size_t)(bq0 + 3) * 1024 + h]);
                sea[T][1] = make_float4(Ea[(size_t)(bq0 + 4) * 1024 + h],
                                        Ea[(size_t)(bq0 + 5) * 1024 + h],
                                        Ea[(size_t)(bq0 + 6) * 1024 + h],
                                        Ea[(size_t)(bq0 + 7) * 1024 + h]);
                sv[T] = vvec[h];
            }
            __syncthreads();
            const float* up = EbT + ((size_t)b * 1024 + h0) * 512 + T;
            f32x2 a0 = {0.f, 0.f}, a1 = {0.f, 0.f}, a2 = {0.f, 0.f}, a3 = {0.f, 0.f};
            #pragma unroll 4
            for (int hh = 0; hh < 64; ++hh) {
                const float  eb = up[(size_t)hh * 512];
                const float4 e0 = sea[hh][0];
                const float4 e1 = sea[hh][1];
                const float  vv = sv[hh];
                f32x2 p0 = f32x2{e0.x, e0.y} * eb + 1.0f;
                f32x2 p1 = f32x2{e0.z, e0.w} * eb + 1.0f;
                f32x2 p2 = f32x2{e1.x, e1.y} * eb + 1.0f;
                f32x2 p3 = f32x2{e1.z, e1.w} * eb + 1.0f;
                f32x2 r0 = {__builtin_amdgcn_rcpf(p0.x), __builtin_amdgcn_rcpf(p0.y)};
                f32x2 r1 = {__builtin_amdgcn_rcpf(p1.x), __builtin_amdgcn_rcpf(p1.y)};
                f32x2 r2 = {__builtin_amdgcn_rcpf(p2.x), __builtin_amdgcn_rcpf(p2.y)};
                f32x2 r3 = {__builtin_amdgcn_rcpf(p3.x), __builtin_amdgcn_rcpf(p3.y)};
                a0 += r0 * vv;
                a1 += r1 * vv;
                a2 += r2 * vv;
                a3 += r3 * vv;
            }
            part[((size_t)(bq0 + 0) * 16 + hc) * 512 + T] = a0.x;
            part[((size_t)(bq0 + 1) * 16 + hc) * 512 + T] = a0.y;
            part[((size_t)(bq0 + 2) * 16 + hc) * 512 + T] = a1.x;
            part[((size_t)(bq0 + 3) * 16 + hc) * 512 + T] = a1.y;
            part[((size_t)(bq0 + 4) * 16 + hc) * 512 + T] = a2.x;
            part[((size_t)(bq0 + 5) * 16 + hc) * 512 + T] = a2.y;
            part[((size_t)(bq0 + 6) * 16 + hc) * 512 + T] = a3.x;
            part[((size_t)(bq0 + 7) * 16 + hc) * 512 + T] = a3.y;
        }
    }
    grid_barrier(bar, 2, NBLK);

    // ================= stage 4: softmax over k (512 virtual blocks) ===========
    {
        float* s_red = (float*)smem;
        const int bqi = BID;
        const float* p = part + (size_t)bqi * 16 * 512;
        float zs = 0.f;
        #pragma unroll
        for (int j = 0; j < 16; ++j) zs += p[j * 512 + T];
        const float z = -2.0f * zs;

        float m = z;
        #pragma unroll
        for (int off = 32; off > 0; off >>= 1)
            m = fmaxf(m, __shfl_xor(m, off, 64));
        if (lane == 0) s_red[wid] = m;
        __syncthreads();
        if (T < 64) {
            float mm2 = (T < 8) ? s_red[T] : -3.0e38f;
            #pragma unroll
            for (int off = 4; off > 0; off >>= 1)
                mm2 = fmaxf(mm2, __shfl_xor(mm2, off, 64));
            if (T == 0) s_red[8] = mm2;
        }
        __syncthreads();
        const float pr = __expf(z - s_red[8]);
        float s = pr;
        #pragma unroll
        for (int off = 32; off > 0; off >>= 1)
            s += __shfl_xor(s, off, 64);
        if (lane == 0) s_red[wid] = s;
        __syncthreads();
        if (T < 64) {
            float ss = (T < 8) ? s_red[T] : 0.f;
            #pragma unroll
            for (int off = 4; off > 0; off >>= 1)
                ss += __shfl_xor(ss, off, 64);
            if (T == 0) s_red[9] = ss;
        }
        __syncthreads();
        const float attn = pr * (1.0f / s_red[9]);
        attn_out[(size_t)bqi * 512 + T] = attn;
        attnb[(size_t)bqi * 512 + T] = (short)f2bf(attn);
    }
    grid_barrier(bar, 3, NBLK);

    // ================= stage 5: PV GEMM (64 virtual blocks) ===================
    if (BID < 64) {
        const int b = BID >> 4, nt = BID & 15;
        const int n0 = nt * 64;
        const short* A = attnb + (size_t)b * 128 * 512;
        const short* B = valT + (size_t)b * 1024 * 512 + (size_t)n0 * 512;

        short* lA = (short*)smem;                       // [2][128][64]
        short* lB = (short*)(smem + 32768);             // [2][64][64]
        f32x4 acc[4];
        #pragma unroll
        for (int i = 0; i < 4; ++i) acc[i] = f32x4{0.f, 0.f, 0.f, 0.f};

        #define PV_STAGE(buf, k0) do {                                          \
            _Pragma("unroll")                                                   \
            for (int it = 0; it < 2; ++it) {                                    \
                const int idx = it * 512 + T;                                   \
                const int row = idx >> 3, c16 = idx & 7;                        \
                const int sc = c16 ^ (row & 7);                                 \
                GLD16(A + (size_t)row * 512 + (k0) + sc * 8,                    \
                      lA + (buf) * 8192 + idx * 8);                             \
            }                                                                   \
            {                                                                   \
                const int idx = T;                                              \
                const int row = idx >> 3, c16 = idx & 7;                        \
                const int sc = c16 ^ (row & 7);                                 \
                GLD16(B + (size_t)row * 512 + (k0) + sc * 8,                    \
                      lB + (buf) * 4096 + idx * 8);                             \
            }                                                                   \
        } while (0)

        #define PV_COMP(buf) do {                                               \
            _Pragma("unroll")                                                   \
            for (int kk = 0; kk < 2; ++kk) {                                    \
                s16x8 af[4], bf1;                                               \
                _Pragma("unroll")                                               \
                for (int i = 0; i < 4; ++i) {                                   \
                    const int rowA = wr * 64 + i * 16 + fr;                     \
                    int offA = rowA * 128 + kk * 64 + fko; offA ^= (rowA & 7) << 4; \
                    af[i] = *(const s16x8*)((const char*)(lA + (buf) * 8192) + offA); \
                }                                                               \
                {                                                               \
                    const int rowB = wc * 16 + fr;                              \
                    int offB = rowB * 128 + kk * 64 + fko; offB ^= (rowB & 7) << 4; \
                    bf1 = *(const s16x8*)((const char*)(lB + (buf) * 4096) + offB); \
                }                                                               \
                _Pragma("unroll")                                               \
                for (int mi = 0; mi < 4; ++mi)                                  \
                    acc[mi] = __builtin_amdgcn_mfma_f32_16x16x32_bf16(          \
                                  af[mi], bf1, acc[mi], 0, 0, 0);               \
            }                                                                   \
        } while (0)

        PV_STAGE(0, 0);
        __syncthreads();
        int cur = 0;
        for (int s = 0; s < 7; ++s) {
            PV_STAGE(cur ^ 1, (s + 1) * 64);
            PV_COMP(cur);
            __syncthreads();
            cur ^= 1;
        }
        PV_COMP(cur);

        const int n = n0 + wc * 16 + fr;
        #pragma unroll
        for (int mi = 0; mi < 4; ++mi) {
            const int m = wr * 64 + mi * 16 + row0;
            #pragma unroll
            for (int j = 0; j < 4; ++j)
                outh[(size_t)(b * 128 + m + j) * 1024 + n] = acc[mi][j];
        }
        #undef PV_STAGE
        #undef PV_COMP
    }
}

extern "C" void kernel_launch(void* const* d_in, const int* in_sizes, int n_in,
                              void* d_out, int out_size, void* d_ws, size_t ws_size,
                              hipStream_t stream)
{
    const float* query = (const float*)d_in[0];
    const float* key   = (const float*)d_in[1];
    const float* value = (const float*)d_in[2];
    const float* Wq    = (const float*)d_in[3];
    const float* bq    = (const float*)d_in[4];
    const float* Wk    = (const float*)d_in[5];
    const float* v     = (const float*)d_in[6];
    float* out = (float*)d_out;

    char* w = (char*)d_ws;
    float* ws_Ea  = (float*)w;                            // 2 MB
    float* ws_EbT = (float*)(w + (2u << 20));             // 8 MB
    short* Qb     = (short*)(w + (10u << 20));            // 1 MB
    short* Kb     = (short*)(w + (11u << 20));            // 4 MB
    short* WqT    = (short*)(w + (15u << 20));            // 2 MB
    short* WkT    = (short*)(w + (17u << 20));            // 2 MB
    short* valT   = (short*)(w + (19u << 20));            // 4 MB
    short* attnb  = (short*)(w + (23u << 20));            // 0.5 MB
    float* part   = (float*)(w + (24u << 20));            // 16 MB
    unsigned* bar = (unsigned*)(w + (40u << 20));         // 64 B barrier slots

    float* out_h    = out;                                // [512][1024]
    float* out_attn = out + (size_t)NB * NTQ * NH;        // [512][512]

    hipMemsetAsync(bar, 0, 64, stream);
    mega_kernel<<<dim3(GRID_BLKS), dim3(512), 0, stream>>>(
        query, key, value, Wq, bq, Wk, v,
        Qb, Kb, WqT, WkT, valT,
        ws_Ea, ws_EbT, part, out_attn, attnb, out_h, bar);
}

// Round 8
// 87.490 us; speedup vs baseline: 4.4846x; 4.4846x over previous
//
#include <hip/hip_runtime.h>
#include <hip/hip_bf16.h>

typedef float f32x4 __attribute__((ext_vector_type(4)));
typedef float f32x2 __attribute__((ext_vector_type(2)));
typedef short s16x8 __attribute__((ext_vector_type(8)));
typedef short s16x4 __attribute__((ext_vector_type(4)));

#define NB  4
#define NTQ 128
#define NTK 512
#define NH  1024

__device__ __forceinline__ unsigned short f2bf(float x) {
    unsigned u = __builtin_bit_cast(unsigned, x);
    u += 0x7FFFu + ((u >> 16) & 1u);          // round-to-nearest-even
    return (unsigned short)(u >> 16);
}

#define K2E  2.8853900817779268f   // 2*log2(e): exp2(K2E*x) = e^{2x}

// async global->LDS 16B: linear LDS dest (wave base + lane*16), per-lane global src
#define GLD16(gp, lp) __builtin_amdgcn_global_load_lds( \
    (const __attribute__((address_space(1))) unsigned int*)(gp), \
    (__attribute__((address_space(3))) unsigned int*)(lp), 16, 0, 0)

// ---------------------------------------------------------------------------
// prep: blocks [0,640): bf16 copy Q|K (float4 coalesced).
// blocks [640,1664): 64x64 transpose-convert tiles: Wq->WqT, Wk->WkT, value->valT.
__global__ __launch_bounds__(256) void prep_kernel(
    const float* __restrict__ Q, const float* __restrict__ K,
    const float* __restrict__ Wq, const float* __restrict__ Wk,
    const float* __restrict__ value,
    short* __restrict__ Qb, short* __restrict__ Kb,
    short* __restrict__ WqT, short* __restrict__ WkT, short* __restrict__ valT)
{
    const int t = threadIdx.x, bx = blockIdx.x;
    if (bx < 640) {   // copy region: blocks [0,128) = Q, [128,640) = K
        const float* src; short* dst; size_t base;
        if (bx < 128) { src = Q; dst = Qb; base = (size_t)bx * 4096; }
        else          { src = K; dst = Kb; base = (size_t)(bx - 128) * 4096; }
        #pragma unroll
        for (int i = 0; i < 4; ++i) {
            const size_t off = base + (size_t)(i * 256 + t) * 4;
            const float4 vv = *(const float4*)(src + off);
            s16x4 o = { (short)f2bf(vv.x), (short)f2bf(vv.y),
                        (short)f2bf(vv.z), (short)f2bf(vv.w) };
            *(s16x4*)(dst + off) = o;
        }
        return;
    }
    // transpose region
    __shared__ float tile[64][65];
    const int i = bx - 640;
    const float* src; short* dst; int Cs, Rs, r0, c0;
    if (i < 256)      { src = Wq; dst = WqT; Cs = 1024; Rs = 1024; r0 = (i >> 4) * 64; c0 = (i & 15) * 64; }
    else if (i < 512) { const int j = i - 256; src = Wk; dst = WkT; Cs = 1024; Rs = 1024; r0 = (j >> 4) * 64; c0 = (j & 15) * 64; }
    else {
        const int j = i - 512, b = j >> 7, ti = j & 127;
        src = value + (size_t)b * 512 * 1024; dst = valT + (size_t)b * 1024 * 512;
        Cs = 1024; Rs = 512; r0 = (ti >> 4) * 64; c0 = (ti & 15) * 64;
    }
    {   // load 64x64 f32 tile, coalesced 256B/row
        const int c = (t & 15) * 4;
        #pragma unroll
        for (int it = 0; it < 4; ++it) {
            const int r = (t >> 4) + it * 16;
            const float4 vv = *(const float4*)(src + (size_t)(r0 + r) * Cs + c0 + c);
            tile[r][c + 0] = vv.x; tile[r][c + 1] = vv.y;
            tile[r][c + 2] = vv.z; tile[r][c + 3] = vv.w;
        }
    }
    __syncthreads();
    {   // write transposed: 128B per 16-lane group
        const int r = (t & 15) * 4;
        #pragma unroll
        for (int it = 0; it < 4; ++it) {
            const int c = (t >> 4) + it * 16;
            s16x4 o = { (short)f2bf(tile[r + 0][c]), (short)f2bf(tile[r + 1][c]),
                        (short)f2bf(tile[r + 2][c]), (short)f2bf(tile[r + 3][c]) };
            *(s16x4*)(dst + (size_t)(c0 + c) * Rs + r0 + r) = o;
        }
    }
}

// ---------------------------------------------------------------------------
// main GEMMs with epilogue exp: swz blocks [0,64): Ea = exp(2*(Q@Wq+bq)) f32;
// [64,320): EbT[b][h][k] = exp(2*(K@Wk)) transposed, stored bf16.
// 128m x 64n tile, BK=64, dbuf LDS via global_load_lds, XOR-swizzled (rule #21).
__global__ __launch_bounds__(256) void mm_kernel(
    const short* __restrict__ Qb, const short* __restrict__ Kb,
    const short* __restrict__ WqT, const short* __restrict__ WkT,
    const float* __restrict__ bq,
    float* __restrict__ Ea_out, unsigned short* __restrict__ EbT)
{
    __shared__ short ldsA[2][128][64];   // 32 KB
    __shared__ short ldsB[2][64][64];    // 16 KB
    const int t = threadIdx.x;
    const int bx0 = blockIdx.x;
    const int bx = (bx0 & 7) * 40 + (bx0 >> 3);   // XCD-chunked swizzle
    const bool g1 = bx < 64;
    const short *A, *B; int m0, n0;
    if (g1) { A = Qb; B = WqT; m0 = (bx >> 4) * 128; n0 = (bx & 15) * 64; }
    else    { const int i = bx - 64; A = Kb; B = WkT; m0 = (i >> 4) * 128; n0 = (i & 15) * 64; }
    A += (size_t)m0 * 1024; B += (size_t)n0 * 1024;

    f32x4 acc[4][2];
    #pragma unroll
    for (int i = 0; i < 4; ++i)
        #pragma unroll
        for (int j = 0; j < 2; ++j) acc[i][j] = f32x4{0.f, 0.f, 0.f, 0.f};

    const int lane = t & 63, wid = t >> 6;
    const int wr = wid >> 1, wc = wid & 1;          // waves 2x2 over (64m,32n)
    const int fr = lane & 15, fko = (lane >> 4) * 16;   // byte offset in 128B row

    #define STAGE_MM(buf, k0) do {                                              \
        _Pragma("unroll")                                                       \
        for (int it = 0; it < 4; ++it) {                                        \
            const int idx = it * 256 + t;                                       \
            const int row = idx >> 3, c16 = idx & 7;                            \
            const int sc = c16 ^ (row & 7);                                     \
            GLD16(A + (size_t)row * 1024 + (k0) + sc * 8,                       \
                  &ldsA[buf][0][0] + idx * 8);                                  \
        }                                                                       \
        _Pragma("unroll")                                                       \
        for (int it = 0; it < 2; ++it) {                                        \
            const int idx = it * 256 + t;                                       \
            const int row = idx >> 3, c16 = idx & 7;                            \
            const int sc = c16 ^ (row & 7);                                     \
            GLD16(B + (size_t)row * 1024 + (k0) + sc * 8,                       \
                  &ldsB[buf][0][0] + idx * 8);                                  \
        }                                                                       \
    } while (0)

    #define COMPUTE_MM(buf) do {                                                \
        _Pragma("unroll")                                                       \
        for (int kk = 0; kk < 2; ++kk) {                                        \
            s16x8 af[4], bfv[2];                                                \
            _Pragma("unroll")                                                   \
            for (int i = 0; i < 4; ++i) {                                       \
                const int rowA = wr * 64 + i * 16 + fr;                         \
                int offA = rowA * 128 + kk * 64 + fko; offA ^= (rowA & 7) << 4; \
                af[i] = *(const s16x8*)((const char*)&ldsA[buf][0][0] + offA);  \
            }                                                                   \
            _Pragma("unroll")                                                   \
            for (int ni = 0; ni < 2; ++ni) {                                    \
                const int rowB = wc * 32 + ni * 16 + fr;                        \
                int offB = rowB * 128 + kk * 64 + fko; offB ^= (rowB & 7) << 4; \
                bfv[ni] = *(const s16x8*)((const char*)&ldsB[buf][0][0] + offB);\
            }                                                                   \
            _Pragma("unroll")                                                   \
            for (int mi = 0; mi < 4; ++mi)                                      \
                _Pragma("unroll")                                               \
                for (int ni = 0; ni < 2; ++ni)                                  \
                    acc[mi][ni] = __builtin_amdgcn_mfma_f32_16x16x32_bf16(      \
                                      af[mi], bfv[ni], acc[mi][ni], 0, 0, 0);   \
        }                                                                       \
    } while (0)

    STAGE_MM(0, 0);
    __syncthreads();
    int cur = 0;
    for (int s = 0; s < 15; ++s) {
        STAGE_MM(cur ^ 1, (s + 1) * 64);
        COMPUTE_MM(cur);
        __syncthreads();
        cur ^= 1;
    }
    COMPUTE_MM(cur);

    // D layout: col = lane&15, row = (lane>>4)*4 + reg
    const int row0 = (lane >> 4) * 4;
    if (g1) {
        #pragma unroll
        for (int ni = 0; ni < 2; ++ni) {
            const int n = n0 + wc * 32 + ni * 16 + fr;
            const float bias = bq[n];
            #pragma unroll
            for (int mi = 0; mi < 4; ++mi) {
                const int m = m0 + wr * 64 + mi * 16 + row0;
                #pragma unroll
                for (int j = 0; j < 4; ++j)
                    Ea_out[(size_t)(m + j) * 1024 + n] =
                        __builtin_amdgcn_exp2f(K2E * (acc[mi][ni][j] + bias));
            }
        }
    } else {
        #pragma unroll
        for (int mi = 0; mi < 4; ++mi) {
            const int m = m0 + wr * 64 + mi * 16 + row0;
            const int b = m >> 9, kk = m & 511;
            #pragma unroll
            for (int ni = 0; ni < 2; ++ni) {
                const int n = n0 + wc * 32 + ni * 16 + fr;
                s16x4 ev;
                #pragma unroll
                for (int j = 0; j < 4; ++j)
                    ev[j] = (short)f2bf(__builtin_amdgcn_exp2f(K2E * acc[mi][ni][j]));
                *(s16x4*)&EbT[((size_t)b * 1024 + n) * 512 + kk] = ev;
            }
        }
    }
    #undef STAGE_MM
    #undef COMPUTE_MM
}

// ---------------------------------------------------------------------------
// fused scores+softmax: block = (b, q-pair), 512 threads = k.
// score z[q][k] = -2 * sum_h v[h] * rcp(1 + Ea[bq][h]*Eb[b][h][k]);
// then in-block softmax over k; writes attn f32 (output) + bf16 copy (for PV).
// grid 256 blocks -> 1 block/CU, trans-pipe floor coverage.
__global__ __launch_bounds__(512) void scores_softmax(
    const unsigned short* __restrict__ EbT, const float* __restrict__ Ea,
    const float* __restrict__ v,
    float* __restrict__ attn_out, short* __restrict__ attnb)
{
    __shared__ float4 s_eav[1024];   // {Ea_q0[h], Ea_q1[h], v[h], -} 16KB
    __shared__ float2 s_red[8];
    const int t = threadIdx.x, bx = blockIdx.x;
    const int b = bx >> 6, q2 = bx & 63;
    const int bq0 = b * 128 + q2 * 2;
    const int lane = t & 63, wid = t >> 6;

    for (int h = t; h < 1024; h += 512)
        s_eav[h] = make_float4(Ea[(size_t)(bq0 + 0) * 1024 + h],
                               Ea[(size_t)(bq0 + 1) * 1024 + h],
                               v[h], 0.f);
    __syncthreads();

    const unsigned short* up = EbT + (size_t)b * 1024 * 512 + t;
    f32x2 acc = {0.f, 0.f};
    #pragma unroll 8
    for (int h = 0; h < 1024; ++h) {
        const unsigned ebb = up[(size_t)h * 512];          // coalesced across lanes
        const float eb = __builtin_bit_cast(float, ebb << 16);
        const float4 e = s_eav[h];                         // ds_read_b128 broadcast
        f32x2 p = f32x2{e.x, e.y} * eb + 1.0f;
        f32x2 r = {__builtin_amdgcn_rcpf(p.x), __builtin_amdgcn_rcpf(p.y)};
        acc += r * e.z;
    }
    const f32x2 z = acc * -2.0f;

    // block max per q (2 q's per thread)
    f32x2 m = z;
    #pragma unroll
    for (int off = 32; off > 0; off >>= 1) {
        m.x = fmaxf(m.x, __shfl_xor(m.x, off, 64));
        m.y = fmaxf(m.y, __shfl_xor(m.y, off, 64));
    }
    if (lane == 0) s_red[wid] = make_float2(m.x, m.y);
    __syncthreads();
    float mx0 = s_red[0].x, mx1 = s_red[0].y;
    #pragma unroll
    for (int w = 1; w < 8; ++w) {
        mx0 = fmaxf(mx0, s_red[w].x);
        mx1 = fmaxf(mx1, s_red[w].y);
    }
    const float p0 = __expf(z.x - mx0);
    const float p1 = __expf(z.y - mx1);
    __syncthreads();   // WAR on s_red

    // block sum per q
    float s0l = p0, s1l = p1;
    #pragma unroll
    for (int off = 32; off > 0; off >>= 1) {
        s0l += __shfl_xor(s0l, off, 64);
        s1l += __shfl_xor(s1l, off, 64);
    }
    if (lane == 0) s_red[wid] = make_float2(s0l, s1l);
    __syncthreads();
    float s0 = 0.f, s1 = 0.f;
    #pragma unroll
    for (int w = 0; w < 8; ++w) { s0 += s_red[w].x; s1 += s_red[w].y; }

    const float a0 = p0 * (1.0f / s0);
    const float a1 = p1 * (1.0f / s1);
    attn_out[(size_t)(bq0 + 0) * 512 + t] = a0;
    attn_out[(size_t)(bq0 + 1) * 512 + t] = a1;
    attnb[(size_t)(bq0 + 0) * 512 + t] = (short)f2bf(a0);
    attnb[(size_t)(bq0 + 1) * 512 + t] = (short)f2bf(a1);
}

// ---------------------------------------------------------------------------
// PV GEMM: outh[b][128][1024] = attnb[b][128][512] @ valT[b][1024][512]^T
// 128m x 64n tile, K=512 (8 steps); grid b*16+nt = 64 blocks
__global__ __launch_bounds__(256) void pv_gemm(
    const short* __restrict__ attnb, const short* __restrict__ valT,
    float* __restrict__ outh)
{
    __shared__ short ldsA[2][128][64];
    __shared__ short ldsB[2][64][64];
    const int t = threadIdx.x, bx = blockIdx.x;
    const int b = bx >> 4, nt = bx & 15;
    const int n0 = nt * 64;
    const short* A = attnb + (size_t)b * 128 * 512;                    // [128][512]
    const short* B = valT + (size_t)b * 1024 * 512 + (size_t)n0 * 512; // [64][512] tile

    f32x4 acc[4][2];
    #pragma unroll
    for (int i = 0; i < 4; ++i)
        #pragma unroll
        for (int j = 0; j < 2; ++j) acc[i][j] = f32x4{0.f, 0.f, 0.f, 0.f};

    const int lane = t & 63, wid = t >> 6;
    const int wr = wid >> 1, wc = wid & 1;
    const int fr = lane & 15, fko = (lane >> 4) * 16;

    #define STAGE_PV(buf, k0) do {                                              \
        _Pragma("unroll")                                                       \
        for (int it = 0; it < 4; ++it) {                                        \
            const int idx = it * 256 + t;                                       \
            const int row = idx >> 3, c16 = idx & 7;                            \
            const int sc = c16 ^ (row & 7);                                     \
            GLD16(A + (size_t)row * 512 + (k0) + sc * 8,                        \
                  &ldsA[buf][0][0] + idx * 8);                                  \
        }                                                                       \
        _Pragma("unroll")                                                       \
        for (int it = 0; it < 2; ++it) {                                        \
            const int idx = it * 256 + t;                                       \
            const int row = idx >> 3, c16 = idx & 7;                            \
            const int sc = c16 ^ (row & 7);                                     \
            GLD16(B + (size_t)row * 512 + (k0) + sc * 8,                        \
                  &ldsB[buf][0][0] + idx * 8);                                  \
        }                                                                       \
    } while (0)

    #define COMPUTE_PV(buf) do {                                                \
        _Pragma("unroll")                                                       \
        for (int kk = 0; kk < 2; ++kk) {                                        \
            s16x8 af[4], bfv[2];                                                \
            _Pragma("unroll")                                                   \
            for (int i = 0; i < 4; ++i) {                                       \
                const int rowA = wr * 64 + i * 16 + fr;                         \
                int offA = rowA * 128 + kk * 64 + fko; offA ^= (rowA & 7) << 4; \
                af[i] = *(const s16x8*)((const char*)&ldsA[buf][0][0] + offA);  \
            }                                                                   \
            _Pragma("unroll")                                                   \
            for (int ni = 0; ni < 2; ++ni) {                                    \
                const int rowB = wc * 32 + ni * 16 + fr;                        \
                int offB = rowB * 128 + kk * 64 + fko; offB ^= (rowB & 7) << 4; \
                bfv[ni] = *(const s16x8*)((const char*)&ldsB[buf][0][0] + offB);\
            }                                                                   \
            _Pragma("unroll")                                                   \
            for (int mi = 0; mi < 4; ++mi)                                      \
                _Pragma("unroll")                                               \
                for (int ni = 0; ni < 2; ++ni)                                  \
                    acc[mi][ni] = __builtin_amdgcn_mfma_f32_16x16x32_bf16(      \
                                      af[mi], bfv[ni], acc[mi][ni], 0, 0, 0);   \
        }                                                                       \
    } while (0)

    STAGE_PV(0, 0);
    __syncthreads();
    int cur = 0;
    for (int s = 0; s < 7; ++s) {
        STAGE_PV(cur ^ 1, (s + 1) * 64);
        COMPUTE_PV(cur);
        __syncthreads();
        cur ^= 1;
    }
    COMPUTE_PV(cur);

    const int row0 = (lane >> 4) * 4;
    #pragma unroll
    for (int ni = 0; ni < 2; ++ni) {
        const int n = n0 + wc * 32 + ni * 16 + fr;
        #pragma unroll
        for (int mi = 0; mi < 4; ++mi) {
            const int m = wr * 64 + mi * 16 + row0;
            #pragma unroll
            for (int j = 0; j < 4; ++j)
                outh[(size_t)(b * 128 + m + j) * 1024 + n] = acc[mi][ni][j];
        }
    }
    #undef STAGE_PV
    #undef COMPUTE_PV
}

extern "C" void kernel_launch(void* const* d_in, const int* in_sizes, int n_in,
                              void* d_out, int out_size, void* d_ws, size_t ws_size,
                              hipStream_t stream)
{
    const float* query = (const float*)d_in[0];
    const float* key   = (const float*)d_in[1];
    const float* value = (const float*)d_in[2];
    const float* Wq    = (const float*)d_in[3];
    const float* bq    = (const float*)d_in[4];
    const float* Wk    = (const float*)d_in[5];
    const float* v     = (const float*)d_in[6];
    float* out = (float*)d_out;

    // workspace layout (19.5 MB):
    char* w = (char*)d_ws;
    float*          ws_Ea  = (float*)w;                       // 2 MB
    unsigned short* ws_EbT = (unsigned short*)(w + (2u << 20)); // 4 MB (bf16)
    short* Qb     = (short*)(w + (6u << 20));                 // 1 MB
    short* Kb     = (short*)(w + (7u << 20));                 // 4 MB
    short* WqT    = (short*)(w + (11u << 20));                // 2 MB
    short* WkT    = (short*)(w + (13u << 20));                // 2 MB
    short* valT   = (short*)(w + (15u << 20));                // 4 MB
    short* attnb  = (short*)(w + (19u << 20));                // 0.5 MB

    float* out_h    = out;                                // [512][1024]
    float* out_attn = out + (size_t)NB * NTQ * NH;        // [512][512]

    prep_kernel   <<<dim3(1664), dim3(256), 0, stream>>>(query, key, Wq, Wk, value,
                                                         Qb, Kb, WqT, WkT, valT);
    mm_kernel     <<<dim3(320),  dim3(256), 0, stream>>>(Qb, Kb, WqT, WkT, bq, ws_Ea, ws_EbT);
    scores_softmax<<<dim3(256),  dim3(512), 0, stream>>>(ws_EbT, ws_Ea, v, out_attn, attnb);
    pv_gemm       <<<dim3(64),   dim3(256), 0, stream>>>(attnb, valT, out_h);
}

// Round 9
// 77.739 us; speedup vs baseline: 5.0472x; 1.1254x over previous
//
#include <hip/hip_runtime.h>
#include <hip/hip_bf16.h>

typedef float f32x4 __attribute__((ext_vector_type(4)));
typedef float f32x2 __attribute__((ext_vector_type(2)));
typedef short s16x8 __attribute__((ext_vector_type(8)));
typedef short s16x4 __attribute__((ext_vector_type(4)));

#define NB  4
#define NTQ 128
#define NTK 512
#define NH  1024

__device__ __forceinline__ unsigned short f2bf(float x) {
    unsigned u = __builtin_bit_cast(unsigned, x);
    u += 0x7FFFu + ((u >> 16) & 1u);          // round-to-nearest-even
    return (unsigned short)(u >> 16);
}

#define K2E  2.8853900817779268f   // 2*log2(e): exp2(K2E*x) = e^{2x}

// async global->LDS 16B: linear LDS dest (wave base + lane*16), per-lane global src
#define GLD16(gp, lp) __builtin_amdgcn_global_load_lds( \
    (const __attribute__((address_space(1))) unsigned int*)(gp), \
    (__attribute__((address_space(3))) unsigned int*)(lp), 16, 0, 0)

// ---------------------------------------------------------------------------
// prep: blocks [0,640): bf16 copy Q|K (float4 coalesced).
// blocks [640,1664): 64x64 transpose-convert tiles: Wq->WqT, Wk->WkT, value->valT.
__global__ __launch_bounds__(256) void prep_kernel(
    const float* __restrict__ Q, const float* __restrict__ K,
    const float* __restrict__ Wq, const float* __restrict__ Wk,
    const float* __restrict__ value,
    short* __restrict__ Qb, short* __restrict__ Kb,
    short* __restrict__ WqT, short* __restrict__ WkT, short* __restrict__ valT)
{
    const int t = threadIdx.x, bx = blockIdx.x;
    if (bx < 640) {   // copy region: blocks [0,128) = Q, [128,640) = K
        const float* src; short* dst; size_t base;
        if (bx < 128) { src = Q; dst = Qb; base = (size_t)bx * 4096; }
        else          { src = K; dst = Kb; base = (size_t)(bx - 128) * 4096; }
        #pragma unroll
        for (int i = 0; i < 4; ++i) {
            const size_t off = base + (size_t)(i * 256 + t) * 4;
            const float4 vv = *(const float4*)(src + off);
            s16x4 o = { (short)f2bf(vv.x), (short)f2bf(vv.y),
                        (short)f2bf(vv.z), (short)f2bf(vv.w) };
            *(s16x4*)(dst + off) = o;
        }
        return;
    }
    // transpose region
    __shared__ float tile[64][65];
    const int i = bx - 640;
    const float* src; short* dst; int Cs, Rs, r0, c0;
    if (i < 256)      { src = Wq; dst = WqT; Cs = 1024; Rs = 1024; r0 = (i >> 4) * 64; c0 = (i & 15) * 64; }
    else if (i < 512) { const int j = i - 256; src = Wk; dst = WkT; Cs = 1024; Rs = 1024; r0 = (j >> 4) * 64; c0 = (j & 15) * 64; }
    else {
        const int j = i - 512, b = j >> 7, ti = j & 127;
        src = value + (size_t)b * 512 * 1024; dst = valT + (size_t)b * 1024 * 512;
        Cs = 1024; Rs = 512; r0 = (ti >> 4) * 64; c0 = (ti & 15) * 64;
    }
    {   // load 64x64 f32 tile, coalesced 256B/row
        const int c = (t & 15) * 4;
        #pragma unroll
        for (int it = 0; it < 4; ++it) {
            const int r = (t >> 4) + it * 16;
            const float4 vv = *(const float4*)(src + (size_t)(r0 + r) * Cs + c0 + c);
            tile[r][c + 0] = vv.x; tile[r][c + 1] = vv.y;
            tile[r][c + 2] = vv.z; tile[r][c + 3] = vv.w;
        }
    }
    __syncthreads();
    {   // write transposed: 128B per 16-lane group
        const int r = (t & 15) * 4;
        #pragma unroll
        for (int it = 0; it < 4; ++it) {
            const int c = (t >> 4) + it * 16;
            s16x4 o = { (short)f2bf(tile[r + 0][c]), (short)f2bf(tile[r + 1][c]),
                        (short)f2bf(tile[r + 2][c]), (short)f2bf(tile[r + 3][c]) };
            *(s16x4*)(dst + (size_t)(c0 + c) * Rs + r0 + r) = o;
        }
    }
}

// ---------------------------------------------------------------------------
// main GEMMs with epilogue exp: swz blocks [0,64): Ea = exp(2*(Q@Wq+bq)) f32;
// [64,320): EbT[b][h][k] = exp(2*(K@Wk)) transposed, stored bf16.
// 128m x 64n tile, BK=64, dbuf LDS via global_load_lds, XOR-swizzled (rule #21).
__global__ __launch_bounds__(256) void mm_kernel(
    const short* __restrict__ Qb, const short* __restrict__ Kb,
    const short* __restrict__ WqT, const short* __restrict__ WkT,
    const float* __restrict__ bq,
    float* __restrict__ Ea_out, unsigned short* __restrict__ EbT)
{
    __shared__ short ldsA[2][128][64];   // 32 KB
    __shared__ short ldsB[2][64][64];    // 16 KB
    const int t = threadIdx.x;
    const int bx0 = blockIdx.x;
    const int bx = (bx0 & 7) * 40 + (bx0 >> 3);   // XCD-chunked swizzle
    const bool g1 = bx < 64;
    const short *A, *B; int m0, n0;
    if (g1) { A = Qb; B = WqT; m0 = (bx >> 4) * 128; n0 = (bx & 15) * 64; }
    else    { const int i = bx - 64; A = Kb; B = WkT; m0 = (i >> 4) * 128; n0 = (i & 15) * 64; }
    A += (size_t)m0 * 1024; B += (size_t)n0 * 1024;

    f32x4 acc[4][2];
    #pragma unroll
    for (int i = 0; i < 4; ++i)
        #pragma unroll
        for (int j = 0; j < 2; ++j) acc[i][j] = f32x4{0.f, 0.f, 0.f, 0.f};

    const int lane = t & 63, wid = t >> 6;
    const int wr = wid >> 1, wc = wid & 1;          // waves 2x2 over (64m,32n)
    const int fr = lane & 15, fko = (lane >> 4) * 16;   // byte offset in 128B row

    #define STAGE_MM(buf, k0) do {                                              \
        _Pragma("unroll")                                                       \
        for (int it = 0; it < 4; ++it) {                                        \
            const int idx = it * 256 + t;                                       \
            const int row = idx >> 3, c16 = idx & 7;                            \
            const int sc = c16 ^ (row & 7);                                     \
            GLD16(A + (size_t)row * 1024 + (k0) + sc * 8,                       \
                  &ldsA[buf][0][0] + idx * 8);                                  \
        }                                                                       \
        _Pragma("unroll")                                                       \
        for (int it = 0; it < 2; ++it) {                                        \
            const int idx = it * 256 + t;                                       \
            const int row = idx >> 3, c16 = idx & 7;                            \
            const int sc = c16 ^ (row & 7);                                     \
            GLD16(B + (size_t)row * 1024 + (k0) + sc * 8,                       \
                  &ldsB[buf][0][0] + idx * 8);                                  \
        }                                                                       \
    } while (0)

    #define COMPUTE_MM(buf) do {                                                \
        _Pragma("unroll")                                                       \
        for (int kk = 0; kk < 2; ++kk) {                                        \
            s16x8 af[4], bfv[2];                                                \
            _Pragma("unroll")                                                   \
            for (int i = 0; i < 4; ++i) {                                       \
                const int rowA = wr * 64 + i * 16 + fr;                         \
                int offA = rowA * 128 + kk * 64 + fko; offA ^= (rowA & 7) << 4; \
                af[i] = *(const s16x8*)((const char*)&ldsA[buf][0][0] + offA);  \
            }                                                                   \
            _Pragma("unroll")                                                   \
            for (int ni = 0; ni < 2; ++ni) {                                    \
                const int rowB = wc * 32 + ni * 16 + fr;                        \
                int offB = rowB * 128 + kk * 64 + fko; offB ^= (rowB & 7) << 4; \
                bfv[ni] = *(const s16x8*)((const char*)&ldsB[buf][0][0] + offB);\
            }                                                                   \
            _Pragma("unroll")                                                   \
            for (int mi = 0; mi < 4; ++mi)                                      \
                _Pragma("unroll")                                               \
                for (int ni = 0; ni < 2; ++ni)                                  \
                    acc[mi][ni] = __builtin_amdgcn_mfma_f32_16x16x32_bf16(      \
                                      af[mi], bfv[ni], acc[mi][ni], 0, 0, 0);   \
        }                                                                       \
    } while (0)

    STAGE_MM(0, 0);
    __syncthreads();
    int cur = 0;
    for (int s = 0; s < 15; ++s) {
        STAGE_MM(cur ^ 1, (s + 1) * 64);
        COMPUTE_MM(cur);
        __syncthreads();
        cur ^= 1;
    }
    COMPUTE_MM(cur);

    // D layout: col = lane&15, row = (lane>>4)*4 + reg
    const int row0 = (lane >> 4) * 4;
    if (g1) {
        #pragma unroll
        for (int ni = 0; ni < 2; ++ni) {
            const int n = n0 + wc * 32 + ni * 16 + fr;
            const float bias = bq[n];
            #pragma unroll
            for (int mi = 0; mi < 4; ++mi) {
                const int m = m0 + wr * 64 + mi * 16 + row0;
                #pragma unroll
                for (int j = 0; j < 4; ++j)
                    Ea_out[(size_t)(m + j) * 1024 + n] =
                        __builtin_amdgcn_exp2f(K2E * (acc[mi][ni][j] + bias));
            }
        }
    } else {
        #pragma unroll
        for (int mi = 0; mi < 4; ++mi) {
            const int m = m0 + wr * 64 + mi * 16 + row0;
            const int b = m >> 9, kk = m & 511;
            #pragma unroll
            for (int ni = 0; ni < 2; ++ni) {
                const int n = n0 + wc * 32 + ni * 16 + fr;
                s16x4 ev;
                #pragma unroll
                for (int j = 0; j < 4; ++j)
                    ev[j] = (short)f2bf(__builtin_amdgcn_exp2f(K2E * acc[mi][ni][j]));
                *(s16x4*)&EbT[((size_t)b * 1024 + n) * 512 + kk] = ev;
            }
        }
    }
    #undef STAGE_MM
    #undef COMPUTE_MM
}

// ---------------------------------------------------------------------------
// fused scores+softmax: block = (b, q-pair), 1024 threads = k(512) x h-half(2).
// Each thread: 512 h-iters x 2 q rcps; halves combined in LDS; in-block softmax.
// grid 256 blocks x 16 waves = 16 waves/CU for L2-latency hiding.
__global__ __launch_bounds__(1024) void scores_softmax(
    const unsigned short* __restrict__ EbT, const float* __restrict__ Ea,
    const float* __restrict__ v,
    float* __restrict__ attn_out, short* __restrict__ attnb)
{
    __shared__ float4 s_eav[1024];   // {Ea_q0[h], Ea_q1[h], v[h], -} 16KB
    __shared__ float2 s_part2[512];  // h-half-1 partials, 4KB
    __shared__ float2 s_red[8];
    const int t = threadIdx.x, bx = blockIdx.x;
    const int b = bx >> 6, q2 = bx & 63;
    const int bq0 = b * 128 + q2 * 2;
    const int k = t & 511, hh = t >> 9;
    const int lane = t & 63, wid = t >> 6;

    s_eav[t] = make_float4(Ea[(size_t)(bq0 + 0) * 1024 + t],
                           Ea[(size_t)(bq0 + 1) * 1024 + t],
                           v[t], 0.f);
    __syncthreads();

    const int h0 = hh * 512;
    const unsigned short* up = EbT + ((size_t)b * 1024 + h0) * 512 + k;
    f32x2 acc = {0.f, 0.f};
    #pragma unroll 8
    for (int h = 0; h < 512; ++h) {
        const unsigned ebb = up[(size_t)h * 512];          // coalesced across lanes
        const float eb = __builtin_bit_cast(float, ebb << 16);
        const float4 e = s_eav[h0 + h];                    // LDS broadcast
        f32x2 p = f32x2{e.x, e.y} * eb + 1.0f;
        f32x2 r = {__builtin_amdgcn_rcpf(p.x), __builtin_amdgcn_rcpf(p.y)};
        acc += r * e.z;
    }
    if (hh == 1) s_part2[k] = make_float2(acc.x, acc.y);
    __syncthreads();

    f32x2 z = {0.f, 0.f};
    if (hh == 0) {
        const float2 o = s_part2[k];
        z = (acc + f32x2{o.x, o.y}) * -2.0f;
    }

    // block max per q (only waves 0-7 hold data; others run harmlessly)
    f32x2 m = z;
    #pragma unroll
    for (int off = 32; off > 0; off >>= 1) {
        m.x = fmaxf(m.x, __shfl_xor(m.x, off, 64));
        m.y = fmaxf(m.y, __shfl_xor(m.y, off, 64));
    }
    if (hh == 0 && lane == 0) s_red[wid] = make_float2(m.x, m.y);
    __syncthreads();
    float mx0 = s_red[0].x, mx1 = s_red[0].y;
    #pragma unroll
    for (int w = 1; w < 8; ++w) {
        mx0 = fmaxf(mx0, s_red[w].x);
        mx1 = fmaxf(mx1, s_red[w].y);
    }
    const float p0 = __expf(z.x - mx0);
    const float p1 = __expf(z.y - mx1);
    __syncthreads();   // WAR on s_red

    // block sum per q
    float s0l = p0, s1l = p1;
    #pragma unroll
    for (int off = 32; off > 0; off >>= 1) {
        s0l += __shfl_xor(s0l, off, 64);
        s1l += __shfl_xor(s1l, off, 64);
    }
    if (hh == 0 && lane == 0) s_red[wid] = make_float2(s0l, s1l);
    __syncthreads();
    if (hh == 0) {
        float s0 = 0.f, s1 = 0.f;
        #pragma unroll
        for (int w = 0; w < 8; ++w) { s0 += s_red[w].x; s1 += s_red[w].y; }
        const float a0 = p0 * (1.0f / s0);
        const float a1 = p1 * (1.0f / s1);
        attn_out[(size_t)(bq0 + 0) * 512 + k] = a0;
        attn_out[(size_t)(bq0 + 1) * 512 + k] = a1;
        attnb[(size_t)(bq0 + 0) * 512 + k] = (short)f2bf(a0);
        attnb[(size_t)(bq0 + 1) * 512 + k] = (short)f2bf(a1);
    }
}

// ---------------------------------------------------------------------------
// PV GEMM: outh[b][128][1024] = attnb[b][128][512] @ valT[b][1024][512]^T
// 128m x 64n tile, K=512 (8 steps); grid b*16+nt = 64 blocks
__global__ __launch_bounds__(256) void pv_gemm(
    const short* __restrict__ attnb, const short* __restrict__ valT,
    float* __restrict__ outh)
{
    __shared__ short ldsA[2][128][64];
    __shared__ short ldsB[2][64][64];
    const int t = threadIdx.x, bx = blockIdx.x;
    const int b = bx >> 4, nt = bx & 15;
    const int n0 = nt * 64;
    const short* A = attnb + (size_t)b * 128 * 512;                    // [128][512]
    const short* B = valT + (size_t)b * 1024 * 512 + (size_t)n0 * 512; // [64][512] tile

    f32x4 acc[4][2];
    #pragma unroll
    for (int i = 0; i < 4; ++i)
        #pragma unroll
        for (int j = 0; j < 2; ++j) acc[i][j] = f32x4{0.f, 0.f, 0.f, 0.f};

    const int lane = t & 63, wid = t >> 6;
    const int wr = wid >> 1, wc = wid & 1;
    const int fr = lane & 15, fko = (lane >> 4) * 16;

    #define STAGE_PV(buf, k0) do {                                              \
        _Pragma("unroll")                                                       \
        for (int it = 0; it < 4; ++it) {                                        \
            const int idx = it * 256 + t;                                       \
            const int row = idx >> 3, c16 = idx & 7;                            \
            const int sc = c16 ^ (row & 7);                                     \
            GLD16(A + (size_t)row * 512 + (k0) + sc * 8,                        \
                  &ldsA[buf][0][0] + idx * 8);                                  \
        }                                                                       \
        _Pragma("unroll")                                                       \
        for (int it = 0; it < 2; ++it) {                                        \
            const int idx = it * 256 + t;                                       \
            const int row = idx >> 3, c16 = idx & 7;                            \
            const int sc = c16 ^ (row & 7);                                     \
            GLD16(B + (size_t)row * 512 + (k0) + sc * 8,                        \
                  &ldsB[buf][0][0] + idx * 8);                                  \
        }                                                                       \
    } while (0)

    #define COMPUTE_PV(buf) do {                                                \
        _Pragma("unroll")                                                       \
        for (int kk = 0; kk < 2; ++kk) {                                        \
            s16x8 af[4], bfv[2];                                                \
            _Pragma("unroll")                                                   \
            for (int i = 0; i < 4; ++i) {                                       \
                const int rowA = wr * 64 + i * 16 + fr;                         \
                int offA = rowA * 128 + kk * 64 + fko; offA ^= (rowA & 7) << 4; \
                af[i] = *(const s16x8*)((const char*)&ldsA[buf][0][0] + offA);  \
            }                                                                   \
            _Pragma("unroll")                                                   \
            for (int ni = 0; ni < 2; ++ni) {                                    \
                const int rowB = wc * 32 + ni * 16 + fr;                        \
                int offB = rowB * 128 + kk * 64 + fko; offB ^= (rowB & 7) << 4; \
                bfv[ni] = *(const s16x8*)((const char*)&ldsB[buf][0][0] + offB);\
            }                                                                   \
            _Pragma("unroll")                                                   \
            for (int mi = 0; mi < 4; ++mi)                                      \
                _Pragma("unroll")                                               \
                for (int ni = 0; ni < 2; ++ni)                                  \
                    acc[mi][ni] = __builtin_amdgcn_mfma_f32_16x16x32_bf16(      \
                                      af[mi], bfv[ni], acc[mi][ni], 0, 0, 0);   \
        }                                                                       \
    } while (0)

    STAGE_PV(0, 0);
    __syncthreads();
    int cur = 0;
    for (int s = 0; s < 7; ++s) {
        STAGE_PV(cur ^ 1, (s + 1) * 64);
        COMPUTE_PV(cur);
        __syncthreads();
        cur ^= 1;
    }
    COMPUTE_PV(cur);

    const int row0 = (lane >> 4) * 4;
    #pragma unroll
    for (int ni = 0; ni < 2; ++ni) {
        const int n = n0 + wc * 32 + ni * 16 + fr;
        #pragma unroll
        for (int mi = 0; mi < 4; ++mi) {
            const int m = wr * 64 + mi * 16 + row0;
            #pragma unroll
            for (int j = 0; j < 4; ++j)
                outh[(size_t)(b * 128 + m + j) * 1024 + n] = acc[mi][ni][j];
        }
    }
    #undef STAGE_PV
    #undef COMPUTE_PV
}

extern "C" void kernel_launch(void* const* d_in, const int* in_sizes, int n_in,
                              void* d_out, int out_size, void* d_ws, size_t ws_size,
                              hipStream_t stream)
{
    const float* query = (const float*)d_in[0];
    const float* key   = (const float*)d_in[1];
    const float* value = (const float*)d_in[2];
    const float* Wq    = (const float*)d_in[3];
    const float* bq    = (const float*)d_in[4];
    const float* Wk    = (const float*)d_in[5];
    const float* v     = (const float*)d_in[6];
    float* out = (float*)d_out;

    // workspace layout (19.5 MB):
    char* w = (char*)d_ws;
    float*          ws_Ea  = (float*)w;                       // 2 MB
    unsigned short* ws_EbT = (unsigned short*)(w + (2u << 20)); // 4 MB (bf16)
    short* Qb     = (short*)(w + (6u << 20));                 // 1 MB
    short* Kb     = (short*)(w + (7u << 20));                 // 4 MB
    short* WqT    = (short*)(w + (11u << 20));                // 2 MB
    short* WkT    = (short*)(w + (13u << 20));                // 2 MB
    short* valT   = (short*)(w + (15u << 20));                // 4 MB
    short* attnb  = (short*)(w + (19u << 20));                // 0.5 MB

    float* out_h    = out;                                // [512][1024]
    float* out_attn = out + (size_t)NB * NTQ * NH;        // [512][512]

    prep_kernel   <<<dim3(1664), dim3(256),  0, stream>>>(query, key, Wq, Wk, value,
                                                          Qb, Kb, WqT, WkT, valT);
    mm_kernel     <<<dim3(320),  dim3(256),  0, stream>>>(Qb, Kb, WqT, WkT, bq, ws_Ea, ws_EbT);
    scores_softmax<<<dim3(256),  dim3(1024), 0, stream>>>(ws_EbT, ws_Ea, v, out_attn, attnb);
    pv_gemm       <<<dim3(64),   dim3(256),  0, stream>>>(attnb, valT, out_h);
}

// Round 10
// 73.291 us; speedup vs baseline: 5.3535x; 1.0607x over previous
//
#include <hip/hip_runtime.h>
#include <hip/hip_bf16.h>

typedef float f32x4 __attribute__((ext_vector_type(4)));
typedef float f32x2 __attribute__((ext_vector_type(2)));
typedef short s16x8 __attribute__((ext_vector_type(8)));
typedef short s16x4 __attribute__((ext_vector_type(4)));

#define NB  4
#define NTQ 128
#define NTK 512
#define NH  1024

__device__ __forceinline__ unsigned short f2bf(float x) {
    unsigned u = __builtin_bit_cast(unsigned, x);
    u += 0x7FFFu + ((u >> 16) & 1u);          // round-to-nearest-even
    return (unsigned short)(u >> 16);
}

#define K2E  2.8853900817779268f   // 2*log2(e): exp2(K2E*x) = e^{2x}

// async global->LDS 16B: linear LDS dest (wave base + lane*16), per-lane global src
#define GLD16(gp, lp) __builtin_amdgcn_global_load_lds( \
    (const __attribute__((address_space(1))) unsigned int*)(gp), \
    (__attribute__((address_space(3))) unsigned int*)(lp), 16, 0, 0)

// ---------------------------------------------------------------------------
// prep: blocks [0,640): bf16 copy Q|K (float4 coalesced).
// blocks [640,1664): 64x64 transpose-convert tiles: Wq->WqT, Wk->WkT, value->valT.
__global__ __launch_bounds__(256) void prep_kernel(
    const float* __restrict__ Q, const float* __restrict__ K,
    const float* __restrict__ Wq, const float* __restrict__ Wk,
    const float* __restrict__ value,
    short* __restrict__ Qb, short* __restrict__ Kb,
    short* __restrict__ WqT, short* __restrict__ WkT, short* __restrict__ valT)
{
    const int t = threadIdx.x, bx = blockIdx.x;
    if (bx < 640) {   // copy region: blocks [0,128) = Q, [128,640) = K
        const float* src; short* dst; size_t base;
        if (bx < 128) { src = Q; dst = Qb; base = (size_t)bx * 4096; }
        else          { src = K; dst = Kb; base = (size_t)(bx - 128) * 4096; }
        #pragma unroll
        for (int i = 0; i < 4; ++i) {
            const size_t off = base + (size_t)(i * 256 + t) * 4;
            const float4 vv = *(const float4*)(src + off);
            s16x4 o = { (short)f2bf(vv.x), (short)f2bf(vv.y),
                        (short)f2bf(vv.z), (short)f2bf(vv.w) };
            *(s16x4*)(dst + off) = o;
        }
        return;
    }
    // transpose region
    __shared__ float tile[64][65];
    const int i = bx - 640;
    const float* src; short* dst; int Cs, Rs, r0, c0;
    if (i < 256)      { src = Wq; dst = WqT; Cs = 1024; Rs = 1024; r0 = (i >> 4) * 64; c0 = (i & 15) * 64; }
    else if (i < 512) { const int j = i - 256; src = Wk; dst = WkT; Cs = 1024; Rs = 1024; r0 = (j >> 4) * 64; c0 = (j & 15) * 64; }
    else {
        const int j = i - 512, b = j >> 7, ti = j & 127;
        src = value + (size_t)b * 512 * 1024; dst = valT + (size_t)b * 1024 * 512;
        Cs = 1024; Rs = 512; r0 = (ti >> 4) * 64; c0 = (ti & 15) * 64;
    }
    {   // load 64x64 f32 tile, coalesced 256B/row
        const int c = (t & 15) * 4;
        #pragma unroll
        for (int it = 0; it < 4; ++it) {
            const int r = (t >> 4) + it * 16;
            const float4 vv = *(const float4*)(src + (size_t)(r0 + r) * Cs + c0 + c);
            tile[r][c + 0] = vv.x; tile[r][c + 1] = vv.y;
            tile[r][c + 2] = vv.z; tile[r][c + 3] = vv.w;
        }
    }
    __syncthreads();
    {   // write transposed: 128B per 16-lane group
        const int r = (t & 15) * 4;
        #pragma unroll
        for (int it = 0; it < 4; ++it) {
            const int c = (t >> 4) + it * 16;
            s16x4 o = { (short)f2bf(tile[r + 0][c]), (short)f2bf(tile[r + 1][c]),
                        (short)f2bf(tile[r + 2][c]), (short)f2bf(tile[r + 3][c]) };
            *(s16x4*)(dst + (size_t)(c0 + c) * Rs + r0 + r) = o;
        }
    }
}

// ---------------------------------------------------------------------------
// main GEMMs with epilogue exp: swz blocks [0,64): Ea = exp(2*(Q@Wq+bq)) f32;
// [64,320): EbT[b][h][k] = exp(2*(K@Wk)) transposed, stored bf16.
// 128m x 64n tile, BK=64, dbuf LDS via global_load_lds, XOR-swizzled (rule #21).
__global__ __launch_bounds__(256) void mm_kernel(
    const short* __restrict__ Qb, const short* __restrict__ Kb,
    const short* __restrict__ WqT, const short* __restrict__ WkT,
    const float* __restrict__ bq,
    float* __restrict__ Ea_out, unsigned short* __restrict__ EbT)
{
    __shared__ short ldsA[2][128][64];   // 32 KB
    __shared__ short ldsB[2][64][64];    // 16 KB
    const int t = threadIdx.x;
    const int bx0 = blockIdx.x;
    const int bx = (bx0 & 7) * 40 + (bx0 >> 3);   // XCD-chunked swizzle
    const bool g1 = bx < 64;
    const short *A, *B; int m0, n0;
    if (g1) { A = Qb; B = WqT; m0 = (bx >> 4) * 128; n0 = (bx & 15) * 64; }
    else    { const int i = bx - 64; A = Kb; B = WkT; m0 = (i >> 4) * 128; n0 = (i & 15) * 64; }
    A += (size_t)m0 * 1024; B += (size_t)n0 * 1024;

    f32x4 acc[4][2];
    #pragma unroll
    for (int i = 0; i < 4; ++i)
        #pragma unroll
        for (int j = 0; j < 2; ++j) acc[i][j] = f32x4{0.f, 0.f, 0.f, 0.f};

    const int lane = t & 63, wid = t >> 6;
    const int wr = wid >> 1, wc = wid & 1;          // waves 2x2 over (64m,32n)
    const int fr = lane & 15, fko = (lane >> 4) * 16;   // byte offset in 128B row

    #define STAGE_MM(buf, k0) do {                                              \
        _Pragma("unroll")                                                       \
        for (int it = 0; it < 4; ++it) {                                        \
            const int idx = it * 256 + t;                                       \
            const int row = idx >> 3, c16 = idx & 7;                            \
            const int sc = c16 ^ (row & 7);                                     \
            GLD16(A + (size_t)row * 1024 + (k0) + sc * 8,                       \
                  &ldsA[buf][0][0] + idx * 8);                                  \
        }                                                                       \
        _Pragma("unroll")                                                       \
        for (int it = 0; it < 2; ++it) {                                        \
            const int idx = it * 256 + t;                                       \
            const int row = idx >> 3, c16 = idx & 7;                            \
            const int sc = c16 ^ (row & 7);                                     \
            GLD16(B + (size_t)row * 1024 + (k0) + sc * 8,                       \
                  &ldsB[buf][0][0] + idx * 8);                                  \
        }                                                                       \
    } while (0)

    #define COMPUTE_MM(buf) do {                                                \
        _Pragma("unroll")                                                       \
        for (int kk = 0; kk < 2; ++kk) {                                        \
            s16x8 af[4], bfv[2];                                                \
            _Pragma("unroll")                                                   \
            for (int i = 0; i < 4; ++i) {                                       \
                const int rowA = wr * 64 + i * 16 + fr;                         \
                int offA = rowA * 128 + kk * 64 + fko; offA ^= (rowA & 7) << 4; \
                af[i] = *(const s16x8*)((const char*)&ldsA[buf][0][0] + offA);  \
            }                                                                   \
            _Pragma("unroll")                                                   \
            for (int ni = 0; ni < 2; ++ni) {                                    \
                const int rowB = wc * 32 + ni * 16 + fr;                        \
                int offB = rowB * 128 + kk * 64 + fko; offB ^= (rowB & 7) << 4; \
                bfv[ni] = *(const s16x8*)((const char*)&ldsB[buf][0][0] + offB);\
            }                                                                   \
            _Pragma("unroll")                                                   \
            for (int mi = 0; mi < 4; ++mi)                                      \
                _Pragma("unroll")                                               \
                for (int ni = 0; ni < 2; ++ni)                                  \
                    acc[mi][ni] = __builtin_amdgcn_mfma_f32_16x16x32_bf16(      \
                                      af[mi], bfv[ni], acc[mi][ni], 0, 0, 0);   \
        }                                                                       \
    } while (0)

    STAGE_MM(0, 0);
    __syncthreads();
    int cur = 0;
    for (int s = 0; s < 15; ++s) {
        STAGE_MM(cur ^ 1, (s + 1) * 64);
        COMPUTE_MM(cur);
        __syncthreads();
        cur ^= 1;
    }
    COMPUTE_MM(cur);

    // D layout: col = lane&15, row = (lane>>4)*4 + reg
    const int row0 = (lane >> 4) * 4;
    if (g1) {
        #pragma unroll
        for (int ni = 0; ni < 2; ++ni) {
            const int n = n0 + wc * 32 + ni * 16 + fr;
            const float bias = bq[n];
            #pragma unroll
            for (int mi = 0; mi < 4; ++mi) {
                const int m = m0 + wr * 64 + mi * 16 + row0;
                #pragma unroll
                for (int j = 0; j < 4; ++j)
                    Ea_out[(size_t)(m + j) * 1024 + n] =
                        __builtin_amdgcn_exp2f(K2E * (acc[mi][ni][j] + bias));
            }
        }
    } else {
        #pragma unroll
        for (int mi = 0; mi < 4; ++mi) {
            const int m = m0 + wr * 64 + mi * 16 + row0;
            const int b = m >> 9, kk = m & 511;
            #pragma unroll
            for (int ni = 0; ni < 2; ++ni) {
                const int n = n0 + wc * 32 + ni * 16 + fr;
                s16x4 ev;
                #pragma unroll
                for (int j = 0; j < 4; ++j)
                    ev[j] = (short)f2bf(__builtin_amdgcn_exp2f(K2E * acc[mi][ni][j]));
                *(s16x4*)&EbT[((size_t)b * 1024 + n) * 512 + kk] = ev;
            }
        }
    }
    #undef STAGE_MM
    #undef COMPUTE_MM
}

// ---------------------------------------------------------------------------
// fused scores+softmax: block = (b, q-pair), 1024 threads = kpair(256) x hquarter(4).
// Thread: 256 h-iters; per iter 1 uint load (2 bf16 k's), 4 rcps (2q x 2k).
// Partials combined via LDS; fused in-block softmax over k.
// grid 256 x 16 waves, 32 KB LDS -> 2 blocks/CU = 32 waves/CU.
__global__ __launch_bounds__(1024, 8) void scores_softmax(
    const unsigned short* __restrict__ EbT, const float* __restrict__ Ea,
    const float* __restrict__ v,
    float* __restrict__ attn_out, short* __restrict__ attnb)
{
    __shared__ float4 s_eav[1024];       // {Ea_q0[h], Ea_q1[h], v[h], -} 16 KB
    __shared__ float  s_part[4][2][512]; // [hq][q][k] partials, 16 KB
    __shared__ float  s_red[16];
    const int t = threadIdx.x, bx = blockIdx.x;
    const int b = bx >> 6, q2 = bx & 63;
    const int bq0 = b * 128 + q2 * 2;
    const int kp = t & 255;              // k-pair: k = 2kp, 2kp+1
    const int hq = t >> 8;               // h-quarter (uniform per wave)
    const int lane = t & 63, wid = t >> 6;

    s_eav[t] = make_float4(Ea[(size_t)(bq0 + 0) * 1024 + t],
                           Ea[(size_t)(bq0 + 1) * 1024 + t],
                           v[t], 0.f);
    __syncthreads();

    const int h0 = hq * 256;
    const unsigned* up = (const unsigned*)(EbT + ((size_t)b * 1024 + h0) * 512) + kp;
    f32x2 a0 = {0.f, 0.f};   // q0 {k0,k1}
    f32x2 a1 = {0.f, 0.f};   // q1 {k0,k1}
    #pragma unroll 8
    for (int h = 0; h < 256; ++h) {
        const unsigned ebb = up[(size_t)h * 256];   // 256B/wave, coalesced
        const float eb0 = __builtin_bit_cast(float, ebb << 16);
        const float eb1 = __builtin_bit_cast(float, ebb & 0xFFFF0000u);
        const float4 e = s_eav[h0 + h];             // uniform addr -> broadcast
        f32x2 p0 = f32x2{eb0, eb1} * e.x + 1.0f;
        f32x2 p1 = f32x2{eb0, eb1} * e.y + 1.0f;
        f32x2 r0 = {__builtin_amdgcn_rcpf(p0.x), __builtin_amdgcn_rcpf(p0.y)};
        f32x2 r1 = {__builtin_amdgcn_rcpf(p1.x), __builtin_amdgcn_rcpf(p1.y)};
        a0 += r0 * e.z;
        a1 += r1 * e.z;
    }
    *(f32x2*)&s_part[hq][0][kp * 2] = a0;
    *(f32x2*)&s_part[hq][1][kp * 2] = a1;
    __syncthreads();

    // combine h-quarters: thread t -> (q = t>>9, k = t&511)
    const int kk = t & 511, qq = t >> 9;
    const float z = -2.0f * (s_part[0][qq][kk] + s_part[1][qq][kk]
                           + s_part[2][qq][kk] + s_part[3][qq][kk]);

    // per-q max over 512 k (waves 0-7 = q0, waves 8-15 = q1)
    float m = z;
    #pragma unroll
    for (int off = 32; off > 0; off >>= 1)
        m = fmaxf(m, __shfl_xor(m, off, 64));
    if (lane == 0) s_red[wid] = m;
    __syncthreads();
    float mx = s_red[qq * 8];
    #pragma unroll
    for (int w = 1; w < 8; ++w) mx = fmaxf(mx, s_red[qq * 8 + w]);
    const float p = __expf(z - mx);
    __syncthreads();   // WAR on s_red

    // per-q sum
    float sl = p;
    #pragma unroll
    for (int off = 32; off > 0; off >>= 1)
        sl += __shfl_xor(sl, off, 64);
    if (lane == 0) s_red[wid] = sl;
    __syncthreads();
    float s = 0.f;
    #pragma unroll
    for (int w = 0; w < 8; ++w) s += s_red[qq * 8 + w];

    const float a = p * (1.0f / s);
    attn_out[(size_t)(bq0 + qq) * 512 + kk] = a;
    attnb[(size_t)(bq0 + qq) * 512 + kk] = (short)f2bf(a);
}

// ---------------------------------------------------------------------------
// PV GEMM: outh[b][128][1024] = attnb[b][128][512] @ valT[b][1024][512]^T
// 128m x 64n tile, K=512 (8 steps); grid b*16+nt = 64 blocks
__global__ __launch_bounds__(256) void pv_gemm(
    const short* __restrict__ attnb, const short* __restrict__ valT,
    float* __restrict__ outh)
{
    __shared__ short ldsA[2][128][64];
    __shared__ short ldsB[2][64][64];
    const int t = threadIdx.x, bx = blockIdx.x;
    const int b = bx >> 4, nt = bx & 15;
    const int n0 = nt * 64;
    const short* A = attnb + (size_t)b * 128 * 512;                    // [128][512]
    const short* B = valT + (size_t)b * 1024 * 512 + (size_t)n0 * 512; // [64][512] tile

    f32x4 acc[4][2];
    #pragma unroll
    for (int i = 0; i < 4; ++i)
        #pragma unroll
        for (int j = 0; j < 2; ++j) acc[i][j] = f32x4{0.f, 0.f, 0.f, 0.f};

    const int lane = t & 63, wid = t >> 6;
    const int wr = wid >> 1, wc = wid & 1;
    const int fr = lane & 15, fko = (lane >> 4) * 16;

    #define STAGE_PV(buf, k0) do {                                              \
        _Pragma("unroll")                                                       \
        for (int it = 0; it < 4; ++it) {                                        \
            const int idx = it * 256 + t;                                       \
            const int row = idx >> 3, c16 = idx & 7;                            \
            const int sc = c16 ^ (row & 7);                                     \
            GLD16(A + (size_t)row * 512 + (k0) + sc * 8,                        \
                  &ldsA[buf][0][0] + idx * 8);                                  \
        }                                                                       \
        _Pragma("unroll")                                                       \
        for (int it = 0; it < 2; ++it) {                                        \
            const int idx = it * 256 + t;                                       \
            const int row = idx >> 3, c16 = idx & 7;                            \
            const int sc = c16 ^ (row & 7);                                     \
            GLD16(B + (size_t)row * 512 + (k0) + sc * 8,                        \
                  &ldsB[buf][0][0] + idx * 8);                                  \
        }                                                                       \
    } while (0)

    #define COMPUTE_PV(buf) do {                                                \
        _Pragma("unroll")                                                       \
        for (int kk = 0; kk < 2; ++kk) {                                        \
            s16x8 af[4], bfv[2];                                                \
            _Pragma("unroll")                                                   \
            for (int i = 0; i < 4; ++i) {                                       \
                const int rowA = wr * 64 + i * 16 + fr;                         \
                int offA = rowA * 128 + kk * 64 + fko; offA ^= (rowA & 7) << 4; \
                af[i] = *(const s16x8*)((const char*)&ldsA[buf][0][0] + offA);  \
            }                                                                   \
            _Pragma("unroll")                                                   \
            for (int ni = 0; ni < 2; ++ni) {                                    \
                const int rowB = wc * 32 + ni * 16 + fr;                        \
                int offB = rowB * 128 + kk * 64 + fko; offB ^= (rowB & 7) << 4; \
                bfv[ni] = *(const s16x8*)((const char*)&ldsB[buf][0][0] + offB);\
            }                                                                   \
            _Pragma("unroll")                                                   \
            for (int mi = 0; mi < 4; ++mi)                                      \
                _Pragma("unroll")                                               \
                for (int ni = 0; ni < 2; ++ni)                                  \
                    acc[mi][ni] = __builtin_amdgcn_mfma_f32_16x16x32_bf16(      \
                                      af[mi], bfv[ni], acc[mi][ni], 0, 0, 0);   \
        }                                                                       \
    } while (0)

    STAGE_PV(0, 0);
    __syncthreads();
    int cur = 0;
    for (int s = 0; s < 7; ++s) {
        STAGE_PV(cur ^ 1, (s + 1) * 64);
        COMPUTE_PV(cur);
        __syncthreads();
        cur ^= 1;
    }
    COMPUTE_PV(cur);

    const int row0 = (lane >> 4) * 4;
    #pragma unroll
    for (int ni = 0; ni < 2; ++ni) {
        const int n = n0 + wc * 32 + ni * 16 + fr;
        #pragma unroll
        for (int mi = 0; mi < 4; ++mi) {
            const int m = wr * 64 + mi * 16 + row0;
            #pragma unroll
            for (int j = 0; j < 4; ++j)
                outh[(size_t)(b * 128 + m + j) * 1024 + n] = acc[mi][ni][j];
        }
    }
    #undef STAGE_PV
    #undef COMPUTE_PV
}

extern "C" void kernel_launch(void* const* d_in, const int* in_sizes, int n_in,
                              void* d_out, int out_size, void* d_ws, size_t ws_size,
                              hipStream_t stream)
{
    const float* query = (const float*)d_in[0];
    const float* key   = (const float*)d_in[1];
    const float* value = (const float*)d_in[2];
    const float* Wq    = (const float*)d_in[3];
    const float* bq    = (const float*)d_in[4];
    const float* Wk    = (const float*)d_in[5];
    const float* v     = (const float*)d_in[6];
    float* out = (float*)d_out;

    // workspace layout (19.5 MB):
    char* w = (char*)d_ws;
    float*          ws_Ea  = (float*)w;                       // 2 MB
    unsigned short* ws_EbT = (unsigned short*)(w + (2u << 20)); // 4 MB (bf16)
    short* Qb     = (short*)(w + (6u << 20));                 // 1 MB
    short* Kb     = (short*)(w + (7u << 20));                 // 4 MB
    short* WqT    = (short*)(w + (11u << 20));                // 2 MB
    short* WkT    = (short*)(w + (13u << 20));                // 2 MB
    short* valT   = (short*)(w + (15u << 20));                // 4 MB
    short* attnb  = (short*)(w + (19u << 20));                // 0.5 MB

    float* out_h    = out;                                // [512][1024]
    float* out_attn = out + (size_t)NB * NTQ * NH;        // [512][512]

    prep_kernel   <<<dim3(1664), dim3(256),  0, stream>>>(query, key, Wq, Wk, value,
                                                          Qb, Kb, WqT, WkT, valT);
    mm_kernel     <<<dim3(320),  dim3(256),  0, stream>>>(Qb, Kb, WqT, WkT, bq, ws_Ea, ws_EbT);
    scores_softmax<<<dim3(256),  dim3(1024), 0, stream>>>(ws_EbT, ws_Ea, v, out_attn, attnb);
    pv_gemm       <<<dim3(64),   dim3(256),  0, stream>>>(attnb, valT, out_h);
}

// Round 11
// 72.658 us; speedup vs baseline: 5.4001x; 1.0087x over previous
//
#include <hip/hip_runtime.h>
#include <hip/hip_bf16.h>

typedef float f32x4 __attribute__((ext_vector_type(4)));
typedef float f32x2 __attribute__((ext_vector_type(2)));
typedef short s16x8 __attribute__((ext_vector_type(8)));
typedef short s16x4 __attribute__((ext_vector_type(4)));

#define NB  4
#define NTQ 128
#define NTK 512
#define NH  1024

__device__ __forceinline__ unsigned short f2bf(float x) {
    unsigned u = __builtin_bit_cast(unsigned, x);
    u += 0x7FFFu + ((u >> 16) & 1u);          // round-to-nearest-even
    return (unsigned short)(u >> 16);
}

#define K2E  2.8853900817779268f   // 2*log2(e): exp2(K2E*x) = e^{2x}

// async global->LDS 16B: linear LDS dest (wave base + lane*16), per-lane global src
#define GLD16(gp, lp) __builtin_amdgcn_global_load_lds( \
    (const __attribute__((address_space(1))) unsigned int*)(gp), \
    (__attribute__((address_space(3))) unsigned int*)(lp), 16, 0, 0)

// ---------------------------------------------------------------------------
// prep: blocks [0,640): bf16 copy Q|K (float4 coalesced).
// blocks [640,1664): 64x64 transpose-convert tiles: Wq->WqT, Wk->WkT, value->valT.
__global__ __launch_bounds__(256) void prep_kernel(
    const float* __restrict__ Q, const float* __restrict__ K,
    const float* __restrict__ Wq, const float* __restrict__ Wk,
    const float* __restrict__ value,
    short* __restrict__ Qb, short* __restrict__ Kb,
    short* __restrict__ WqT, short* __restrict__ WkT, short* __restrict__ valT)
{
    const int t = threadIdx.x, bx = blockIdx.x;
    if (bx < 640) {   // copy region: blocks [0,128) = Q, [128,640) = K
        const float* src; short* dst; size_t base;
        if (bx < 128) { src = Q; dst = Qb; base = (size_t)bx * 4096; }
        else          { src = K; dst = Kb; base = (size_t)(bx - 128) * 4096; }
        #pragma unroll
        for (int i = 0; i < 4; ++i) {
            const size_t off = base + (size_t)(i * 256 + t) * 4;
            const float4 vv = *(const float4*)(src + off);
            s16x4 o = { (short)f2bf(vv.x), (short)f2bf(vv.y),
                        (short)f2bf(vv.z), (short)f2bf(vv.w) };
            *(s16x4*)(dst + off) = o;
        }
        return;
    }
    // transpose region
    __shared__ float tile[64][65];
    const int i = bx - 640;
    const float* src; short* dst; int Cs, Rs, r0, c0;
    if (i < 256)      { src = Wq; dst = WqT; Cs = 1024; Rs = 1024; r0 = (i >> 4) * 64; c0 = (i & 15) * 64; }
    else if (i < 512) { const int j = i - 256; src = Wk; dst = WkT; Cs = 1024; Rs = 1024; r0 = (j >> 4) * 64; c0 = (j & 15) * 64; }
    else {
        const int j = i - 512, b = j >> 7, ti = j & 127;
        src = value + (size_t)b * 512 * 1024; dst = valT + (size_t)b * 1024 * 512;
        Cs = 1024; Rs = 512; r0 = (ti >> 4) * 64; c0 = (ti & 15) * 64;
    }
    {   // load 64x64 f32 tile, coalesced 256B/row
        const int c = (t & 15) * 4;
        #pragma unroll
        for (int it = 0; it < 4; ++it) {
            const int r = (t >> 4) + it * 16;
            const float4 vv = *(const float4*)(src + (size_t)(r0 + r) * Cs + c0 + c);
            tile[r][c + 0] = vv.x; tile[r][c + 1] = vv.y;
            tile[r][c + 2] = vv.z; tile[r][c + 3] = vv.w;
        }
    }
    __syncthreads();
    {   // write transposed: 128B per 16-lane group
        const int r = (t & 15) * 4;
        #pragma unroll
        for (int it = 0; it < 4; ++it) {
            const int c = (t >> 4) + it * 16;
            s16x4 o = { (short)f2bf(tile[r + 0][c]), (short)f2bf(tile[r + 1][c]),
                        (short)f2bf(tile[r + 2][c]), (short)f2bf(tile[r + 3][c]) };
            *(s16x4*)(dst + (size_t)(c0 + c) * Rs + r0 + r) = o;
        }
    }
}

// ---------------------------------------------------------------------------
// main GEMMs with epilogue exp: swz blocks [0,64): Ea = exp(2*(Q@Wq+bq)) f32;
// [64,320): EbT[b][h][k] = exp(2*(K@Wk)) transposed, stored bf16.
// 128m x 64n tile, BK=64, dbuf LDS via global_load_lds, XOR-swizzled (rule #21).
__global__ __launch_bounds__(256) void mm_kernel(
    const short* __restrict__ Qb, const short* __restrict__ Kb,
    const short* __restrict__ WqT, const short* __restrict__ WkT,
    const float* __restrict__ bq,
    float* __restrict__ Ea_out, unsigned short* __restrict__ EbT)
{
    __shared__ short ldsA[2][128][64];   // 32 KB
    __shared__ short ldsB[2][64][64];    // 16 KB
    const int t = threadIdx.x;
    const int bx0 = blockIdx.x;
    const int bx = (bx0 & 7) * 40 + (bx0 >> 3);   // XCD-chunked swizzle
    const bool g1 = bx < 64;
    const short *A, *B; int m0, n0;
    if (g1) { A = Qb; B = WqT; m0 = (bx >> 4) * 128; n0 = (bx & 15) * 64; }
    else    { const int i = bx - 64; A = Kb; B = WkT; m0 = (i >> 4) * 128; n0 = (i & 15) * 64; }
    A += (size_t)m0 * 1024; B += (size_t)n0 * 1024;

    f32x4 acc[4][2];
    #pragma unroll
    for (int i = 0; i < 4; ++i)
        #pragma unroll
        for (int j = 0; j < 2; ++j) acc[i][j] = f32x4{0.f, 0.f, 0.f, 0.f};

    const int lane = t & 63, wid = t >> 6;
    const int wr = wid >> 1, wc = wid & 1;          // waves 2x2 over (64m,32n)
    const int fr = lane & 15, fko = (lane >> 4) * 16;   // byte offset in 128B row

    #define STAGE_MM(buf, k0) do {                                              \
        _Pragma("unroll")                                                       \
        for (int it = 0; it < 4; ++it) {                                        \
            const int idx = it * 256 + t;                                       \
            const int row = idx >> 3, c16 = idx & 7;                            \
            const int sc = c16 ^ (row & 7);                                     \
            GLD16(A + (size_t)row * 1024 + (k0) + sc * 8,                       \
                  &ldsA[buf][0][0] + idx * 8);                                  \
        }                                                                       \
        _Pragma("unroll")                                                       \
        for (int it = 0; it < 2; ++it) {                                        \
            const int idx = it * 256 + t;                                       \
            const int row = idx >> 3, c16 = idx & 7;                            \
            const int sc = c16 ^ (row & 7);                                     \
            GLD16(B + (size_t)row * 1024 + (k0) + sc * 8,                       \
                  &ldsB[buf][0][0] + idx * 8);                                  \
        }                                                                       \
    } while (0)

    #define COMPUTE_MM(buf) do {                                                \
        _Pragma("unroll")                                                       \
        for (int kk = 0; kk < 2; ++kk) {                                        \
            s16x8 af[4], bfv[2];                                                \
            _Pragma("unroll")                                                   \
            for (int i = 0; i < 4; ++i) {                                       \
                const int rowA = wr * 64 + i * 16 + fr;                         \
                int offA = rowA * 128 + kk * 64 + fko; offA ^= (rowA & 7) << 4; \
                af[i] = *(const s16x8*)((const char*)&ldsA[buf][0][0] + offA);  \
            }                                                                   \
            _Pragma("unroll")                                                   \
            for (int ni = 0; ni < 2; ++ni) {                                    \
                const int rowB = wc * 32 + ni * 16 + fr;                        \
                int offB = rowB * 128 + kk * 64 + fko; offB ^= (rowB & 7) << 4; \
                bfv[ni] = *(const s16x8*)((const char*)&ldsB[buf][0][0] + offB);\
            }                                                                   \
            _Pragma("unroll")                                                   \
            for (int mi = 0; mi < 4; ++mi)                                      \
                _Pragma("unroll")                                               \
                for (int ni = 0; ni < 2; ++ni)                                  \
                    acc[mi][ni] = __builtin_amdgcn_mfma_f32_16x16x32_bf16(      \
                                      af[mi], bfv[ni], acc[mi][ni], 0, 0, 0);   \
        }                                                                       \
    } while (0)

    STAGE_MM(0, 0);
    __syncthreads();
    int cur = 0;
    for (int s = 0; s < 15; ++s) {
        STAGE_MM(cur ^ 1, (s + 1) * 64);
        COMPUTE_MM(cur);
        __syncthreads();
        cur ^= 1;
    }
    COMPUTE_MM(cur);

    // D layout: col = lane&15, row = (lane>>4)*4 + reg
    const int row0 = (lane >> 4) * 4;
    if (g1) {
        #pragma unroll
        for (int ni = 0; ni < 2; ++ni) {
            const int n = n0 + wc * 32 + ni * 16 + fr;
            const float bias = bq[n];
            #pragma unroll
            for (int mi = 0; mi < 4; ++mi) {
                const int m = m0 + wr * 64 + mi * 16 + row0;
                #pragma unroll
                for (int j = 0; j < 4; ++j)
                    Ea_out[(size_t)(m + j) * 1024 + n] =
                        __builtin_amdgcn_exp2f(K2E * (acc[mi][ni][j] + bias));
            }
        }
    } else {
        #pragma unroll
        for (int mi = 0; mi < 4; ++mi) {
            const int m = m0 + wr * 64 + mi * 16 + row0;
            const int b = m >> 9, kk = m & 511;
            #pragma unroll
            for (int ni = 0; ni < 2; ++ni) {
                const int n = n0 + wc * 32 + ni * 16 + fr;
                s16x4 ev;
                #pragma unroll
                for (int j = 0; j < 4; ++j)
                    ev[j] = (short)f2bf(__builtin_amdgcn_exp2f(K2E * acc[mi][ni][j]));
                *(s16x4*)&EbT[((size_t)b * 1024 + n) * 512 + kk] = ev;
            }
        }
    }
    #undef STAGE_MM
    #undef COMPUTE_MM
}

// ---------------------------------------------------------------------------
// scores: z[bq][k] = -2 * sum_h v[h] * rcp(1 + Ea[bq][h]*Eb[b][h][k])
// grid 512 = (b,q-pair,k-half); 1024 threads = kp(128) x h-eighth(8).
// 2 blocks/CU = 32 waves/CU; per iter: 1 uint load (2 k), 4 rcps (2q x 2k).
__global__ __launch_bounds__(1024, 8) void scores_z(
    const unsigned short* __restrict__ EbT, const float* __restrict__ Ea,
    const float* __restrict__ v, float* __restrict__ zout)
{
    __shared__ float4 s_eav[1024];       // {Ea_q0[h], Ea_q1[h], v[h], -} 16 KB
    __shared__ float  s_part[8][2][256]; // [hq][q][k-in-half] partials, 16 KB
    const int t = threadIdx.x, bx = blockIdx.x;
    const int kh = bx & 1;
    const int bq2 = bx >> 1;             // 0..255
    const int b = bq2 >> 6, q2 = bq2 & 63;
    const int bq0 = b * 128 + q2 * 2;
    const int kp = t & 127;              // k-pair within half
    const int hq = t >> 7;               // h-eighth (uniform per wave)

    s_eav[t] = make_float4(Ea[(size_t)(bq0 + 0) * 1024 + t],
                           Ea[(size_t)(bq0 + 1) * 1024 + t],
                           v[t], 0.f);
    __syncthreads();

    const int h0 = hq * 128;
    const unsigned* up = (const unsigned*)(EbT + ((size_t)b * 1024 + h0) * 512)
                         + kh * 128 + kp;
    f32x2 a0 = {0.f, 0.f};   // q0 {k0,k1}
    f32x2 a1 = {0.f, 0.f};   // q1 {k0,k1}
    #pragma unroll 8
    for (int h = 0; h < 128; ++h) {
        const unsigned ebb = up[(size_t)h * 256];   // 256B/wave, coalesced
        const float eb0 = __builtin_bit_cast(float, ebb << 16);
        const float eb1 = __builtin_bit_cast(float, ebb & 0xFFFF0000u);
        const float4 e = s_eav[h0 + h];             // uniform addr -> broadcast
        f32x2 p0 = f32x2{eb0, eb1} * e.x + 1.0f;
        f32x2 p1 = f32x2{eb0, eb1} * e.y + 1.0f;
        f32x2 r0 = {__builtin_amdgcn_rcpf(p0.x), __builtin_amdgcn_rcpf(p0.y)};
        f32x2 r1 = {__builtin_amdgcn_rcpf(p1.x), __builtin_amdgcn_rcpf(p1.y)};
        a0 += r0 * e.z;
        a1 += r1 * e.z;
    }
    *(f32x2*)&s_part[hq][0][kp * 2] = a0;
    *(f32x2*)&s_part[hq][1][kp * 2] = a1;
    __syncthreads();

    if (t < 512) {
        const int kk = t & 255, qq = t >> 8;
        float z = 0.f;
        #pragma unroll
        for (int j = 0; j < 8; ++j) z += s_part[j][qq][kk];
        zout[(size_t)(bq0 + qq) * 512 + kh * 256 + kk] = -2.0f * z;
    }
}

// ---------------------------------------------------------------------------
// softmax over k: one block per (b,q); writes attn f32 (output) + bf16 (for PV)
__global__ __launch_bounds__(512) void softmax_kernel(
    const float* __restrict__ zin, float* __restrict__ attn_out,
    short* __restrict__ attnb)
{
    __shared__ float s_red[16];
    const int t = threadIdx.x, bqi = blockIdx.x;
    const float z = zin[(size_t)bqi * 512 + t];
    const int lane = t & 63, wid = t >> 6;

    float m = z;
    #pragma unroll
    for (int off = 32; off > 0; off >>= 1)
        m = fmaxf(m, __shfl_xor(m, off, 64));
    if (lane == 0) s_red[wid] = m;
    __syncthreads();
    float mx = s_red[0];
    #pragma unroll
    for (int w = 1; w < 8; ++w) mx = fmaxf(mx, s_red[w]);
    const float p = __expf(z - mx);
    __syncthreads();   // WAR on s_red

    float sl = p;
    #pragma unroll
    for (int off = 32; off > 0; off >>= 1)
        sl += __shfl_xor(sl, off, 64);
    if (lane == 0) s_red[wid] = sl;
    __syncthreads();
    float s = 0.f;
    #pragma unroll
    for (int w = 0; w < 8; ++w) s += s_red[w];

    const float a = p * (1.0f / s);
    attn_out[(size_t)bqi * 512 + t] = a;
    attnb[(size_t)bqi * 512 + t] = (short)f2bf(a);
}

// ---------------------------------------------------------------------------
// PV GEMM: outh[b][128][1024] = attnb[b][128][512] @ valT[b][1024][512]^T
// 128m x 64n tile, K=512 (8 steps); grid b*16+nt = 64 blocks
__global__ __launch_bounds__(256) void pv_gemm(
    const short* __restrict__ attnb, const short* __restrict__ valT,
    float* __restrict__ outh)
{
    __shared__ short ldsA[2][128][64];
    __shared__ short ldsB[2][64][64];
    const int t = threadIdx.x, bx = blockIdx.x;
    const int b = bx >> 4, nt = bx & 15;
    const int n0 = nt * 64;
    const short* A = attnb + (size_t)b * 128 * 512;                    // [128][512]
    const short* B = valT + (size_t)b * 1024 * 512 + (size_t)n0 * 512; // [64][512] tile

    f32x4 acc[4][2];
    #pragma unroll
    for (int i = 0; i < 4; ++i)
        #pragma unroll
        for (int j = 0; j < 2; ++j) acc[i][j] = f32x4{0.f, 0.f, 0.f, 0.f};

    const int lane = t & 63, wid = t >> 6;
    const int wr = wid >> 1, wc = wid & 1;
    const int fr = lane & 15, fko = (lane >> 4) * 16;

    #define STAGE_PV(buf, k0) do {                                              \
        _Pragma("unroll")                                                       \
        for (int it = 0; it < 4; ++it) {                                        \
            const int idx = it * 256 + t;                                       \
            const int row = idx >> 3, c16 = idx & 7;                            \
            const int sc = c16 ^ (row & 7);                                     \
            GLD16(A + (size_t)row * 512 + (k0) + sc * 8,                        \
                  &ldsA[buf][0][0] + idx * 8);                                  \
        }                                                                       \
        _Pragma("unroll")                                                       \
        for (int it = 0; it < 2; ++it) {                                        \
            const int idx = it * 256 + t;                                       \
            const int row = idx >> 3, c16 = idx & 7;                            \
            const int sc = c16 ^ (row & 7);                                     \
            GLD16(B + (size_t)row * 512 + (k0) + sc * 8,                        \
                  &ldsB[buf][0][0] + idx * 8);                                  \
        }                                                                       \
    } while (0)

    #define COMPUTE_PV(buf) do {                                                \
        _Pragma("unroll")                                                       \
        for (int kk = 0; kk < 2; ++kk) {                                        \
            s16x8 af[4], bfv[2];                                                \
            _Pragma("unroll")                                                   \
            for (int i = 0; i < 4; ++i) {                                       \
                const int rowA = wr * 64 + i * 16 + fr;                         \
                int offA = rowA * 128 + kk * 64 + fko; offA ^= (rowA & 7) << 4; \
                af[i] = *(const s16x8*)((const char*)&ldsA[buf][0][0] + offA);  \
            }                                                                   \
            _Pragma("unroll")                                                   \
            for (int ni = 0; ni < 2; ++ni) {                                    \
                const int rowB = wc * 32 + ni * 16 + fr;                        \
                int offB = rowB * 128 + kk * 64 + fko; offB ^= (rowB & 7) << 4; \
                bfv[ni] = *(const s16x8*)((const char*)&ldsB[buf][0][0] + offB);\
            }                                                                   \
            _Pragma("unroll")                                                   \
            for (int mi = 0; mi < 4; ++mi)                                      \
                _Pragma("unroll")                                               \
                for (int ni = 0; ni < 2; ++ni)                                  \
                    acc[mi][ni] = __builtin_amdgcn_mfma_f32_16x16x32_bf16(      \
                                      af[mi], bfv[ni], acc[mi][ni], 0, 0, 0);   \
        }                                                                       \
    } while (0)

    STAGE_PV(0, 0);
    __syncthreads();
    int cur = 0;
    for (int s = 0; s < 7; ++s) {
        STAGE_PV(cur ^ 1, (s + 1) * 64);
        COMPUTE_PV(cur);
        __syncthreads();
        cur ^= 1;
    }
    COMPUTE_PV(cur);

    const int row0 = (lane >> 4) * 4;
    #pragma unroll
    for (int ni = 0; ni < 2; ++ni) {
        const int n = n0 + wc * 32 + ni * 16 + fr;
        #pragma unroll
        for (int mi = 0; mi < 4; ++mi) {
            const int m = wr * 64 + mi * 16 + row0;
            #pragma unroll
            for (int j = 0; j < 4; ++j)
                outh[(size_t)(b * 128 + m + j) * 1024 + n] = acc[mi][ni][j];
        }
    }
    #undef STAGE_PV
    #undef COMPUTE_PV
}

extern "C" void kernel_launch(void* const* d_in, const int* in_sizes, int n_in,
                              void* d_out, int out_size, void* d_ws, size_t ws_size,
                              hipStream_t stream)
{
    const float* query = (const float*)d_in[0];
    const float* key   = (const float*)d_in[1];
    const float* value = (const float*)d_in[2];
    const float* Wq    = (const float*)d_in[3];
    const float* bq    = (const float*)d_in[4];
    const float* Wk    = (const float*)d_in[5];
    const float* v     = (const float*)d_in[6];
    float* out = (float*)d_out;

    // workspace layout (21 MB):
    char* w = (char*)d_ws;
    float*          ws_Ea  = (float*)w;                       // 2 MB
    unsigned short* ws_EbT = (unsigned short*)(w + (2u << 20)); // 4 MB (bf16)
    short* Qb     = (short*)(w + (6u << 20));                 // 1 MB
    short* Kb     = (short*)(w + (7u << 20));                 // 4 MB
    short* WqT    = (short*)(w + (11u << 20));                // 2 MB
    short* WkT    = (short*)(w + (13u << 20));                // 2 MB
    short* valT   = (short*)(w + (15u << 20));                // 4 MB
    short* attnb  = (short*)(w + (19u << 20));                // 0.5 MB
    float* zbuf   = (float*)(w + (20u << 20));                // 1 MB

    float* out_h    = out;                                // [512][1024]
    float* out_attn = out + (size_t)NB * NTQ * NH;        // [512][512]

    prep_kernel   <<<dim3(1664), dim3(256),  0, stream>>>(query, key, Wq, Wk, value,
                                                          Qb, Kb, WqT, WkT, valT);
    mm_kernel     <<<dim3(320),  dim3(256),  0, stream>>>(Qb, Kb, WqT, WkT, bq, ws_Ea, ws_EbT);
    scores_z      <<<dim3(512),  dim3(1024), 0, stream>>>(ws_EbT, ws_Ea, v, zbuf);
    softmax_kernel<<<dim3(512),  dim3(512),  0, stream>>>(zbuf, out_attn, attnb);
    pv_gemm       <<<dim3(64),   dim3(256),  0, stream>>>(attnb, valT, out_h);
}

// Round 12
// 71.441 us; speedup vs baseline: 5.4921x; 1.0170x over previous
//
#include <hip/hip_runtime.h>
#include <hip/hip_bf16.h>

typedef float f32x4 __attribute__((ext_vector_type(4)));
typedef float f32x2 __attribute__((ext_vector_type(2)));
typedef short s16x8 __attribute__((ext_vector_type(8)));
typedef short s16x4 __attribute__((ext_vector_type(4)));

#define NB  4
#define NTQ 128
#define NTK 512
#define NH  1024

__device__ __forceinline__ unsigned short f2bf(float x) {
    unsigned u = __builtin_bit_cast(unsigned, x);
    u += 0x7FFFu + ((u >> 16) & 1u);          // round-to-nearest-even
    return (unsigned short)(u >> 16);
}

#define K2E  2.8853900817779268f   // 2*log2(e): exp2(K2E*x) = e^{2x}

// async global->LDS 16B: linear LDS dest (wave base + lane*16), per-lane global src
#define GLD16(gp, lp) __builtin_amdgcn_global_load_lds( \
    (const __attribute__((address_space(1))) unsigned int*)(gp), \
    (__attribute__((address_space(3))) unsigned int*)(lp), 16, 0, 0)

// ---------------------------------------------------------------------------
// prep: blocks [0,640): bf16 copy Q|K (float4 coalesced).
// blocks [640,1664): 64x64 transpose-convert tiles: Wq->WqT, Wk->WkT, value->valT.
__global__ __launch_bounds__(256) void prep_kernel(
    const float* __restrict__ Q, const float* __restrict__ K,
    const float* __restrict__ Wq, const float* __restrict__ Wk,
    const float* __restrict__ value,
    short* __restrict__ Qb, short* __restrict__ Kb,
    short* __restrict__ WqT, short* __restrict__ WkT, short* __restrict__ valT)
{
    const int t = threadIdx.x, bx = blockIdx.x;
    if (bx < 640) {   // copy region: blocks [0,128) = Q, [128,640) = K
        const float* src; short* dst; size_t base;
        if (bx < 128) { src = Q; dst = Qb; base = (size_t)bx * 4096; }
        else          { src = K; dst = Kb; base = (size_t)(bx - 128) * 4096; }
        #pragma unroll
        for (int i = 0; i < 4; ++i) {
            const size_t off = base + (size_t)(i * 256 + t) * 4;
            const float4 vv = *(const float4*)(src + off);
            s16x4 o = { (short)f2bf(vv.x), (short)f2bf(vv.y),
                        (short)f2bf(vv.z), (short)f2bf(vv.w) };
            *(s16x4*)(dst + off) = o;
        }
        return;
    }
    // transpose region
    __shared__ float tile[64][65];
    const int i = bx - 640;
    const float* src; short* dst; int Cs, Rs, r0, c0;
    if (i < 256)      { src = Wq; dst = WqT; Cs = 1024; Rs = 1024; r0 = (i >> 4) * 64; c0 = (i & 15) * 64; }
    else if (i < 512) { const int j = i - 256; src = Wk; dst = WkT; Cs = 1024; Rs = 1024; r0 = (j >> 4) * 64; c0 = (j & 15) * 64; }
    else {
        const int j = i - 512, b = j >> 7, ti = j & 127;
        src = value + (size_t)b * 512 * 1024; dst = valT + (size_t)b * 1024 * 512;
        Cs = 1024; Rs = 512; r0 = (ti >> 4) * 64; c0 = (ti & 15) * 64;
    }
    {   // load 64x64 f32 tile, coalesced 256B/row
        const int c = (t & 15) * 4;
        #pragma unroll
        for (int it = 0; it < 4; ++it) {
            const int r = (t >> 4) + it * 16;
            const float4 vv = *(const float4*)(src + (size_t)(r0 + r) * Cs + c0 + c);
            tile[r][c + 0] = vv.x; tile[r][c + 1] = vv.y;
            tile[r][c + 2] = vv.z; tile[r][c + 3] = vv.w;
        }
    }
    __syncthreads();
    {   // write transposed: 128B per 16-lane group
        const int r = (t & 15) * 4;
        #pragma unroll
        for (int it = 0; it < 4; ++it) {
            const int c = (t >> 4) + it * 16;
            s16x4 o = { (short)f2bf(tile[r + 0][c]), (short)f2bf(tile[r + 1][c]),
                        (short)f2bf(tile[r + 2][c]), (short)f2bf(tile[r + 3][c]) };
            *(s16x4*)(dst + (size_t)(c0 + c) * Rs + r0 + r) = o;
        }
    }
}

// ---------------------------------------------------------------------------
// main GEMMs with epilogue exp: swz blocks [0,64): Ea = exp(2*(Q@Wq+bq)) f32;
// [64,320): EbT[b][h][k] = exp(2*(K@Wk)) transposed, stored bf16.
// 128m x 64n tile, BK=64, dbuf LDS via global_load_lds, XOR-swizzled (rule #21).
__global__ __launch_bounds__(256) void mm_kernel(
    const short* __restrict__ Qb, const short* __restrict__ Kb,
    const short* __restrict__ WqT, const short* __restrict__ WkT,
    const float* __restrict__ bq,
    float* __restrict__ Ea_out, unsigned short* __restrict__ EbT)
{
    __shared__ short ldsA[2][128][64];   // 32 KB
    __shared__ short ldsB[2][64][64];    // 16 KB
    const int t = threadIdx.x;
    const int bx0 = blockIdx.x;
    const int bx = (bx0 & 7) * 40 + (bx0 >> 3);   // XCD-chunked swizzle
    const bool g1 = bx < 64;
    const short *A, *B; int m0, n0;
    if (g1) { A = Qb; B = WqT; m0 = (bx >> 4) * 128; n0 = (bx & 15) * 64; }
    else    { const int i = bx - 64; A = Kb; B = WkT; m0 = (i >> 4) * 128; n0 = (i & 15) * 64; }
    A += (size_t)m0 * 1024; B += (size_t)n0 * 1024;

    f32x4 acc[4][2];
    #pragma unroll
    for (int i = 0; i < 4; ++i)
        #pragma unroll
        for (int j = 0; j < 2; ++j) acc[i][j] = f32x4{0.f, 0.f, 0.f, 0.f};

    const int lane = t & 63, wid = t >> 6;
    const int wr = wid >> 1, wc = wid & 1;          // waves 2x2 over (64m,32n)
    const int fr = lane & 15, fko = (lane >> 4) * 16;   // byte offset in 128B row

    #define STAGE_MM(buf, k0) do {                                              \
        _Pragma("unroll")                                                       \
        for (int it = 0; it < 4; ++it) {                                        \
            const int idx = it * 256 + t;                                       \
            const int row = idx >> 3, c16 = idx & 7;                            \
            const int sc = c16 ^ (row & 7);                                     \
            GLD16(A + (size_t)row * 1024 + (k0) + sc * 8,                       \
                  &ldsA[buf][0][0] + idx * 8);                                  \
        }                                                                       \
        _Pragma("unroll")                                                       \
        for (int it = 0; it < 2; ++it) {                                        \
            const int idx = it * 256 + t;                                       \
            const int row = idx >> 3, c16 = idx & 7;                            \
            const int sc = c16 ^ (row & 7);                                     \
            GLD16(B + (size_t)row * 1024 + (k0) + sc * 8,                       \
                  &ldsB[buf][0][0] + idx * 8);                                  \
        }                                                                       \
    } while (0)

    #define COMPUTE_MM(buf) do {                                                \
        _Pragma("unroll")                                                       \
        for (int kk = 0; kk < 2; ++kk) {                                        \
            s16x8 af[4], bfv[2];                                                \
            _Pragma("unroll")                                                   \
            for (int i = 0; i < 4; ++i) {                                       \
                const int rowA = wr * 64 + i * 16 + fr;                         \
                int offA = rowA * 128 + kk * 64 + fko; offA ^= (rowA & 7) << 4; \
                af[i] = *(const s16x8*)((const char*)&ldsA[buf][0][0] + offA);  \
            }                                                                   \
            _Pragma("unroll")                                                   \
            for (int ni = 0; ni < 2; ++ni) {                                    \
                const int rowB = wc * 32 + ni * 16 + fr;                        \
                int offB = rowB * 128 + kk * 64 + fko; offB ^= (rowB & 7) << 4; \
                bfv[ni] = *(const s16x8*)((const char*)&ldsB[buf][0][0] + offB);\
            }                                                                   \
            _Pragma("unroll")                                                   \
            for (int mi = 0; mi < 4; ++mi)                                      \
                _Pragma("unroll")                                               \
                for (int ni = 0; ni < 2; ++ni)                                  \
                    acc[mi][ni] = __builtin_amdgcn_mfma_f32_16x16x32_bf16(      \
                                      af[mi], bfv[ni], acc[mi][ni], 0, 0, 0);   \
        }                                                                       \
    } while (0)

    STAGE_MM(0, 0);
    __syncthreads();
    int cur = 0;
    for (int s = 0; s < 15; ++s) {
        STAGE_MM(cur ^ 1, (s + 1) * 64);
        COMPUTE_MM(cur);
        __syncthreads();
        cur ^= 1;
    }
    COMPUTE_MM(cur);

    // D layout: col = lane&15, row = (lane>>4)*4 + reg
    const int row0 = (lane >> 4) * 4;
    if (g1) {
        #pragma unroll
        for (int ni = 0; ni < 2; ++ni) {
            const int n = n0 + wc * 32 + ni * 16 + fr;
            const float bias = bq[n];
            #pragma unroll
            for (int mi = 0; mi < 4; ++mi) {
                const int m = m0 + wr * 64 + mi * 16 + row0;
                #pragma unroll
                for (int j = 0; j < 4; ++j)
                    Ea_out[(size_t)(m + j) * 1024 + n] =
                        __builtin_amdgcn_exp2f(K2E * (acc[mi][ni][j] + bias));
            }
        }
    } else {
        #pragma unroll
        for (int mi = 0; mi < 4; ++mi) {
            const int m = m0 + wr * 64 + mi * 16 + row0;
            const int b = m >> 9, kk = m & 511;
            #pragma unroll
            for (int ni = 0; ni < 2; ++ni) {
                const int n = n0 + wc * 32 + ni * 16 + fr;
                s16x4 ev;
                #pragma unroll
                for (int j = 0; j < 4; ++j)
                    ev[j] = (short)f2bf(__builtin_amdgcn_exp2f(K2E * acc[mi][ni][j]));
                *(s16x4*)&EbT[((size_t)b * 1024 + n) * 512 + kk] = ev;
            }
        }
    }
    #undef STAGE_MM
    #undef COMPUTE_MM
}

// ---------------------------------------------------------------------------
// scores: z[bq][k] = -2 * sum_h v[h] * rcp(1 + Ea[bq][h]*Eb[b][h][k])
// XCD-pinned: (b, k-half) = bid & 7 -> all blocks of one (b,kh) land on ONE XCD
// (round-robin dispatch), so per-XCD L2 working set = EbT slice (512 KB) +
// Ea[b] (512 KB) -> L2-resident, ~200cy hits instead of 17 MB HBM re-fetch.
// grid 512; 1024 threads = kp(128) x h-eighth(8); 2 blocks/CU = 32 waves/CU.
__global__ __launch_bounds__(1024, 8) void scores_z(
    const unsigned short* __restrict__ EbT, const float* __restrict__ Ea,
    const float* __restrict__ v, float* __restrict__ zout)
{
    __shared__ float4 s_eav[1024];       // {Ea_q0[h], Ea_q1[h], v[h], -} 16 KB
    __shared__ float  s_part[8][2][256]; // [hq][q][k-in-half] partials, 16 KB
    const int t = threadIdx.x, bx = blockIdx.x;
    const int combo = bx & 7;            // XCD id: (b, k-half)
    const int b  = combo >> 1, kh = combo & 1;
    const int q2 = bx >> 3;              // 0..63
    const int bq0 = b * 128 + q2 * 2;
    const int kp = t & 127;              // k-pair within half
    const int hq = t >> 7;               // h-eighth (uniform per wave)

    s_eav[t] = make_float4(Ea[(size_t)(bq0 + 0) * 1024 + t],
                           Ea[(size_t)(bq0 + 1) * 1024 + t],
                           v[t], 0.f);
    __syncthreads();

    const int h0 = hq * 128;
    const unsigned* up = (const unsigned*)(EbT + ((size_t)b * 1024 + h0) * 512)
                         + kh * 128 + kp;
    f32x2 a0 = {0.f, 0.f};   // q0 {k0,k1}
    f32x2 a1 = {0.f, 0.f};   // q1 {k0,k1}
    #pragma unroll 8
    for (int h = 0; h < 128; ++h) {
        const unsigned ebb = up[(size_t)h * 256];   // 256B/wave, coalesced
        const float eb0 = __builtin_bit_cast(float, ebb << 16);
        const float eb1 = __builtin_bit_cast(float, ebb & 0xFFFF0000u);
        const float4 e = s_eav[h0 + h];             // uniform addr -> broadcast
        f32x2 p0 = f32x2{eb0, eb1} * e.x + 1.0f;
        f32x2 p1 = f32x2{eb0, eb1} * e.y + 1.0f;
        f32x2 r0 = {__builtin_amdgcn_rcpf(p0.x), __builtin_amdgcn_rcpf(p0.y)};
        f32x2 r1 = {__builtin_amdgcn_rcpf(p1.x), __builtin_amdgcn_rcpf(p1.y)};
        a0 += r0 * e.z;
        a1 += r1 * e.z;
    }
    *(f32x2*)&s_part[hq][0][kp * 2] = a0;
    *(f32x2*)&s_part[hq][1][kp * 2] = a1;
    __syncthreads();

    if (t < 512) {
        const int kk = t & 255, qq = t >> 8;
        float z = 0.f;
        #pragma unroll
        for (int j = 0; j < 8; ++j) z += s_part[j][qq][kk];
        zout[(size_t)(bq0 + qq) * 512 + kh * 256 + kk] = -2.0f * z;
    }
}

// ---------------------------------------------------------------------------
// softmax over k: one block per (b,q); writes attn f32 (output) + bf16 (for PV)
__global__ __launch_bounds__(512) void softmax_kernel(
    const float* __restrict__ zin, float* __restrict__ attn_out,
    short* __restrict__ attnb)
{
    __shared__ float s_red[16];
    const int t = threadIdx.x, bqi = blockIdx.x;
    const float z = zin[(size_t)bqi * 512 + t];
    const int lane = t & 63, wid = t >> 6;

    float m = z;
    #pragma unroll
    for (int off = 32; off > 0; off >>= 1)
        m = fmaxf(m, __shfl_xor(m, off, 64));
    if (lane == 0) s_red[wid] = m;
    __syncthreads();
    float mx = s_red[0];
    #pragma unroll
    for (int w = 1; w < 8; ++w) mx = fmaxf(mx, s_red[w]);
    const float p = __expf(z - mx);
    __syncthreads();   // WAR on s_red

    float sl = p;
    #pragma unroll
    for (int off = 32; off > 0; off >>= 1)
        sl += __shfl_xor(sl, off, 64);
    if (lane == 0) s_red[wid] = sl;
    __syncthreads();
    float s = 0.f;
    #pragma unroll
    for (int w = 0; w < 8; ++w) s += s_red[w];

    const float a = p * (1.0f / s);
    attn_out[(size_t)bqi * 512 + t] = a;
    attnb[(size_t)bqi * 512 + t] = (short)f2bf(a);
}

// ---------------------------------------------------------------------------
// PV GEMM: outh[b][128][1024] = attnb[b][128][512] @ valT[b][1024][512]^T
// 128m x 64n tile, K=512 (8 steps); grid b*16+nt = 64 blocks
__global__ __launch_bounds__(256) void pv_gemm(
    const short* __restrict__ attnb, const short* __restrict__ valT,
    float* __restrict__ outh)
{
    __shared__ short ldsA[2][128][64];
    __shared__ short ldsB[2][64][64];
    const int t = threadIdx.x, bx = blockIdx.x;
    const int b = bx >> 4, nt = bx & 15;
    const int n0 = nt * 64;
    const short* A = attnb + (size_t)b * 128 * 512;                    // [128][512]
    const short* B = valT + (size_t)b * 1024 * 512 + (size_t)n0 * 512; // [64][512] tile

    f32x4 acc[4][2];
    #pragma unroll
    for (int i = 0; i < 4; ++i)
        #pragma unroll
        for (int j = 0; j < 2; ++j) acc[i][j] = f32x4{0.f, 0.f, 0.f, 0.f};

    const int lane = t & 63, wid = t >> 6;
    const int wr = wid >> 1, wc = wid & 1;
    const int fr = lane & 15, fko = (lane >> 4) * 16;

    #define STAGE_PV(buf, k0) do {                                              \
        _Pragma("unroll")                                                       \
        for (int it = 0; it < 4; ++it) {                                        \
            const int idx = it * 256 + t;                                       \
            const int row = idx >> 3, c16 = idx & 7;                            \
            const int sc = c16 ^ (row & 7);                                     \
            GLD16(A + (size_t)row * 512 + (k0) + sc * 8,                        \
                  &ldsA[buf][0][0] + idx * 8);                                  \
        }                                                                       \
        _Pragma("unroll")                                                       \
        for (int it = 0; it < 2; ++it) {                                        \
            const int idx = it * 256 + t;                                       \
            const int row = idx >> 3, c16 = idx & 7;                            \
            const int sc = c16 ^ (row & 7);                                     \
            GLD16(B + (size_t)row * 512 + (k0) + sc * 8,                        \
                  &ldsB[buf][0][0] + idx * 8);                                  \
        }                                                                       \
    } while (0)

    #define COMPUTE_PV(buf) do {                                                \
        _Pragma("unroll")                                                       \
        for (int kk = 0; kk < 2; ++kk) {                                        \
            s16x8 af[4], bfv[2];                                                \
            _Pragma("unroll")                                                   \
            for (int i = 0; i < 4; ++i) {                                       \
                const int rowA = wr * 64 + i * 16 + fr;                         \
                int offA = rowA * 128 + kk * 64 + fko; offA ^= (rowA & 7) << 4; \
                af[i] = *(const s16x8*)((const char*)&ldsA[buf][0][0] + offA);  \
            }                                                                   \
            _Pragma("unroll")                                                   \
            for (int ni = 0; ni < 2; ++ni) {                                    \
                const int rowB = wc * 32 + ni * 16 + fr;                        \
                int offB = rowB * 128 + kk * 64 + fko; offB ^= (rowB & 7) << 4; \
                bfv[ni] = *(const s16x8*)((const char*)&ldsB[buf][0][0] + offB);\
            }                                                                   \
            _Pragma("unroll")                                                   \
            for (int mi = 0; mi < 4; ++mi)                                      \
                _Pragma("unroll")                                               \
                for (int ni = 0; ni < 2; ++ni)                                  \
                    acc[mi][ni] = __builtin_amdgcn_mfma_f32_16x16x32_bf16(      \
                                      af[mi], bfv[ni], acc[mi][ni], 0, 0, 0);   \
        }                                                                       \
    } while (0)

    STAGE_PV(0, 0);
    __syncthreads();
    int cur = 0;
    for (int s = 0; s < 7; ++s) {
        STAGE_PV(cur ^ 1, (s + 1) * 64);
        COMPUTE_PV(cur);
        __syncthreads();
        cur ^= 1;
    }
    COMPUTE_PV(cur);

    const int row0 = (lane >> 4) * 4;
    #pragma unroll
    for (int ni = 0; ni < 2; ++ni) {
        const int n = n0 + wc * 32 + ni * 16 + fr;
        #pragma unroll
        for (int mi = 0; mi < 4; ++mi) {
            const int m = wr * 64 + mi * 16 + row0;
            #pragma unroll
            for (int j = 0; j < 4; ++j)
                outh[(size_t)(b * 128 + m + j) * 1024 + n] = acc[mi][ni][j];
        }
    }
    #undef STAGE_PV
    #undef COMPUTE_PV
}

extern "C" void kernel_launch(void* const* d_in, const int* in_sizes, int n_in,
                              void* d_out, int out_size, void* d_ws, size_t ws_size,
                              hipStream_t stream)
{
    const float* query = (const float*)d_in[0];
    const float* key   = (const float*)d_in[1];
    const float* value = (const float*)d_in[2];
    const float* Wq    = (const float*)d_in[3];
    const float* bq    = (const float*)d_in[4];
    const float* Wk    = (const float*)d_in[5];
    const float* v     = (const float*)d_in[6];
    float* out = (float*)d_out;

    // workspace layout (21 MB):
    char* w = (char*)d_ws;
    float*          ws_Ea  = (float*)w;                       // 2 MB
    unsigned short* ws_EbT = (unsigned short*)(w + (2u << 20)); // 4 MB (bf16)
    short* Qb     = (short*)(w + (6u << 20));                 // 1 MB
    short* Kb     = (short*)(w + (7u << 20));                 // 4 MB
    short* WqT    = (short*)(w + (11u << 20));                // 2 MB
    short* WkT    = (short*)(w + (13u << 20));                // 2 MB
    short* valT   = (short*)(w + (15u << 20));                // 4 MB
    short* attnb  = (short*)(w + (19u << 20));                // 0.5 MB
    float* zbuf   = (float*)(w + (20u << 20));                // 1 MB

    float* out_h    = out;                                // [512][1024]
    float* out_attn = out + (size_t)NB * NTQ * NH;        // [512][512]

    prep_kernel   <<<dim3(1664), dim3(256),  0, stream>>>(query, key, Wq, Wk, value,
                                                          Qb, Kb, WqT, WkT, valT);
    mm_kernel     <<<dim3(320),  dim3(256),  0, stream>>>(Qb, Kb, WqT, WkT, bq, ws_Ea, ws_EbT);
    scores_z      <<<dim3(512),  dim3(1024), 0, stream>>>(ws_EbT, ws_Ea, v, zbuf);
    softmax_kernel<<<dim3(512),  dim3(512),  0, stream>>>(zbuf, out_attn, attnb);
    pv_gemm       <<<dim3(64),   dim3(256),  0, stream>>>(attnb, valT, out_h);
}

// Round 14
// 70.338 us; speedup vs baseline: 5.5782x; 1.0157x over previous
//
#include <hip/hip_runtime.h>
#include <hip/hip_bf16.h>

typedef float f32x4 __attribute__((ext_vector_type(4)));
typedef float f32x2 __attribute__((ext_vector_type(2)));
typedef short s16x8 __attribute__((ext_vector_type(8)));
typedef short s16x4 __attribute__((ext_vector_type(4)));

#define NB  4
#define NTQ 128
#define NTK 512
#define NH  1024

__device__ __forceinline__ unsigned short f2bf(float x) {
    unsigned u = __builtin_bit_cast(unsigned, x);
    u += 0x7FFFu + ((u >> 16) & 1u);          // round-to-nearest-even
    return (unsigned short)(u >> 16);
}

#define K2E  2.8853900817779268f   // 2*log2(e): exp2(K2E*x) = e^{2x}

// async global->LDS 16B: linear LDS dest (wave base + lane*16), per-lane global src
#define GLD16(gp, lp) __builtin_amdgcn_global_load_lds( \
    (const __attribute__((address_space(1))) unsigned int*)(gp), \
    (__attribute__((address_space(3))) unsigned int*)(lp), 16, 0, 0)

// ---------------------------------------------------------------------------
// prep: blocks [0,640): bf16 copy Q|K (float4 coalesced).
// blocks [640,1664): 64x64 transpose-convert tiles: Wq->WqT, Wk->WkT, value->valT.
__global__ __launch_bounds__(256) void prep_kernel(
    const float* __restrict__ Q, const float* __restrict__ K,
    const float* __restrict__ Wq, const float* __restrict__ Wk,
    const float* __restrict__ value,
    short* __restrict__ Qb, short* __restrict__ Kb,
    short* __restrict__ WqT, short* __restrict__ WkT, short* __restrict__ valT)
{
    const int t = threadIdx.x, bx = blockIdx.x;
    if (bx < 640) {   // copy region: blocks [0,128) = Q, [128,640) = K
        const float* src; short* dst; size_t base;
        if (bx < 128) { src = Q; dst = Qb; base = (size_t)bx * 4096; }
        else          { src = K; dst = Kb; base = (size_t)(bx - 128) * 4096; }
        #pragma unroll
        for (int i = 0; i < 4; ++i) {
            const size_t off = base + (size_t)(i * 256 + t) * 4;
            const float4 vv = *(const float4*)(src + off);
            s16x4 o = { (short)f2bf(vv.x), (short)f2bf(vv.y),
                        (short)f2bf(vv.z), (short)f2bf(vv.w) };
            *(s16x4*)(dst + off) = o;
        }
        return;
    }
    // transpose region
    __shared__ float tile[64][65];
    const int i = bx - 640;
    const float* src; short* dst; int Cs, Rs, r0, c0;
    if (i < 256)      { src = Wq; dst = WqT; Cs = 1024; Rs = 1024; r0 = (i >> 4) * 64; c0 = (i & 15) * 64; }
    else if (i < 512) { const int j = i - 256; src = Wk; dst = WkT; Cs = 1024; Rs = 1024; r0 = (j >> 4) * 64; c0 = (j & 15) * 64; }
    else {
        const int j = i - 512, b = j >> 7, ti = j & 127;
        src = value + (size_t)b * 512 * 1024; dst = valT + (size_t)b * 1024 * 512;
        Cs = 1024; Rs = 512; r0 = (ti >> 4) * 64; c0 = (ti & 15) * 64;
    }
    {   // load 64x64 f32 tile, coalesced 256B/row
        const int c = (t & 15) * 4;
        #pragma unroll
        for (int it = 0; it < 4; ++it) {
            const int r = (t >> 4) + it * 16;
            const float4 vv = *(const float4*)(src + (size_t)(r0 + r) * Cs + c0 + c);
            tile[r][c + 0] = vv.x; tile[r][c + 1] = vv.y;
            tile[r][c + 2] = vv.z; tile[r][c + 3] = vv.w;
        }
    }
    __syncthreads();
    {   // write transposed: 128B per 16-lane group
        const int r = (t & 15) * 4;
        #pragma unroll
        for (int it = 0; it < 4; ++it) {
            const int c = (t >> 4) + it * 16;
            s16x4 o = { (short)f2bf(tile[r + 0][c]), (short)f2bf(tile[r + 1][c]),
                        (short)f2bf(tile[r + 2][c]), (short)f2bf(tile[r + 3][c]) };
            *(s16x4*)(dst + (size_t)(c0 + c) * Rs + r0 + r) = o;
        }
    }
}

// ---------------------------------------------------------------------------
// main GEMMs with epilogue exp: swz blocks [0,64): Ea = exp(2*(Q@Wq+bq)) f32;
// [64,320): EbT[b][h][k] = exp(2*(K@Wk)) transposed, stored bf16.
// 128m x 64n tile, BK=64, dbuf LDS via global_load_lds, XOR-swizzled (rule #21).
__global__ __launch_bounds__(256) void mm_kernel(
    const short* __restrict__ Qb, const short* __restrict__ Kb,
    const short* __restrict__ WqT, const short* __restrict__ WkT,
    const float* __restrict__ bq,
    float* __restrict__ Ea_out, unsigned short* __restrict__ EbT)
{
    __shared__ short ldsA[2][128][64];   // 32 KB
    __shared__ short ldsB[2][64][64];    // 16 KB
    const int t = threadIdx.x;
    const int bx0 = blockIdx.x;
    const int bx = (bx0 & 7) * 40 + (bx0 >> 3);   // XCD-chunked swizzle
    const bool g1 = bx < 64;
    const short *A, *B; int m0, n0;
    if (g1) { A = Qb; B = WqT; m0 = (bx >> 4) * 128; n0 = (bx & 15) * 64; }
    else    { const int i = bx - 64; A = Kb; B = WkT; m0 = (i >> 4) * 128; n0 = (i & 15) * 64; }
    A += (size_t)m0 * 1024; B += (size_t)n0 * 1024;

    f32x4 acc[4][2];
    #pragma unroll
    for (int i = 0; i < 4; ++i)
        #pragma unroll
        for (int j = 0; j < 2; ++j) acc[i][j] = f32x4{0.f, 0.f, 0.f, 0.f};

    const int lane = t & 63, wid = t >> 6;
    const int wr = wid >> 1, wc = wid & 1;          // waves 2x2 over (64m,32n)
    const int fr = lane & 15, fko = (lane >> 4) * 16;   // byte offset in 128B row

    #define STAGE_MM(buf, k0) do {                                              \
        _Pragma("unroll")                                                       \
        for (int it = 0; it < 4; ++it) {                                        \
            const int idx = it * 256 + t;                                       \
            const int row = idx >> 3, c16 = idx & 7;                            \
            const int sc = c16 ^ (row & 7);                                     \
            GLD16(A + (size_t)row * 1024 + (k0) + sc * 8,                       \
                  &ldsA[buf][0][0] + idx * 8);                                  \
        }                                                                       \
        _Pragma("unroll")                                                       \
        for (int it = 0; it < 2; ++it) {                                        \
            const int idx = it * 256 + t;                                       \
            const int row = idx >> 3, c16 = idx & 7;                            \
            const int sc = c16 ^ (row & 7);                                     \
            GLD16(B + (size_t)row * 1024 + (k0) + sc * 8,                       \
                  &ldsB[buf][0][0] + idx * 8);                                  \
        }                                                                       \
    } while (0)

    #define COMPUTE_MM(buf) do {                                                \
        _Pragma("unroll")                                                       \
        for (int kk = 0; kk < 2; ++kk) {                                        \
            s16x8 af[4], bfv[2];                                                \
            _Pragma("unroll")                                                   \
            for (int i = 0; i < 4; ++i) {                                       \
                const int rowA = wr * 64 + i * 16 + fr;                         \
                int offA = rowA * 128 + kk * 64 + fko; offA ^= (rowA & 7) << 4; \
                af[i] = *(const s16x8*)((const char*)&ldsA[buf][0][0] + offA);  \
            }                                                                   \
            _Pragma("unroll")                                                   \
            for (int ni = 0; ni < 2; ++ni) {                                    \
                const int rowB = wc * 32 + ni * 16 + fr;                        \
                int offB = rowB * 128 + kk * 64 + fko; offB ^= (rowB & 7) << 4; \
                bfv[ni] = *(const s16x8*)((const char*)&ldsB[buf][0][0] + offB);\
            }                                                                   \
            _Pragma("unroll")                                                   \
            for (int mi = 0; mi < 4; ++mi)                                      \
                _Pragma("unroll")                                               \
                for (int ni = 0; ni < 2; ++ni)                                  \
                    acc[mi][ni] = __builtin_amdgcn_mfma_f32_16x16x32_bf16(      \
                                      af[mi], bfv[ni], acc[mi][ni], 0, 0, 0);   \
        }                                                                       \
    } while (0)

    STAGE_MM(0, 0);
    __syncthreads();
    int cur = 0;
    for (int s = 0; s < 15; ++s) {
        STAGE_MM(cur ^ 1, (s + 1) * 64);
        COMPUTE_MM(cur);
        __syncthreads();
        cur ^= 1;
    }
    COMPUTE_MM(cur);

    // D layout: col = lane&15, row = (lane>>4)*4 + reg
    const int row0 = (lane >> 4) * 4;
    if (g1) {
        #pragma unroll
        for (int ni = 0; ni < 2; ++ni) {
            const int n = n0 + wc * 32 + ni * 16 + fr;
            const float bias = bq[n];
            #pragma unroll
            for (int mi = 0; mi < 4; ++mi) {
                const int m = m0 + wr * 64 + mi * 16 + row0;
                #pragma unroll
                for (int j = 0; j < 4; ++j)
                    Ea_out[(size_t)(m + j) * 1024 + n] =
                        __builtin_amdgcn_exp2f(K2E * (acc[mi][ni][j] + bias));
            }
        }
    } else {
        #pragma unroll
        for (int mi = 0; mi < 4; ++mi) {
            const int m = m0 + wr * 64 + mi * 16 + row0;
            const int b = m >> 9, kk = m & 511;
            #pragma unroll
            for (int ni = 0; ni < 2; ++ni) {
                const int n = n0 + wc * 32 + ni * 16 + fr;
                s16x4 ev;
                #pragma unroll
                for (int j = 0; j < 4; ++j)
                    ev[j] = (short)f2bf(__builtin_amdgcn_exp2f(K2E * acc[mi][ni][j]));
                *(s16x4*)&EbT[((size_t)b * 1024 + n) * 512 + kk] = ev;
            }
        }
    }
    #undef STAGE_MM
    #undef COMPUTE_MM
}

// ---------------------------------------------------------------------------
// scores: z[bq][k] = -2 * sum_h v[h] * rcp(1 + Ea[bq][h]*Eb[b][h][k])
// 8 elements (2q x 4k) per thread-iteration: 1 uint2 load + ~16 VALU + 8 rcp.
// grid 512, XCD-pinned combo = bid&7; 1024 thr = kq(64) x h-slice(16);
// 2 blocks/CU = 8 waves/SIMD. (R13 bug fixed: h-stride is 128 uint2 = 512 bf16.)
__global__ __launch_bounds__(1024, 8) void scores_z(
    const unsigned short* __restrict__ EbT, const float* __restrict__ Ea,
    const float* __restrict__ v, float* __restrict__ zout)
{
    __shared__ float4 s_eav[1024];        // {Ea_q0[h], Ea_q1[h], v[h], -} 16 KB
    __shared__ float  s_part[16][2][256]; // [hs][q][k-in-half] partials, 32 KB
    const int t = threadIdx.x, bx = blockIdx.x;
    const int combo = bx & 7;             // XCD id: (b, k-half)
    const int b  = combo >> 1, kh = combo & 1;
    const int q2 = bx >> 3;               // 0..63
    const int bq0 = b * 128 + q2 * 2;
    const int kq = t & 63;                // k-quad: k_local = 4kq..4kq+3
    const int hs = t >> 6;                // h-slice (uniform per wave)

    s_eav[t] = make_float4(Ea[(size_t)(bq0 + 0) * 1024 + t],
                           Ea[(size_t)(bq0 + 1) * 1024 + t],
                           v[t], 0.f);
    __syncthreads();

    const int h0 = hs * 64;
    const uint2* up = (const uint2*)(EbT + ((size_t)(b * 1024 + h0)) * 512
                                     + kh * 256 + kq * 4);
    f32x2 a00 = {0.f, 0.f}, a01 = {0.f, 0.f};   // q0: {k0,k1}, {k2,k3}
    f32x2 a10 = {0.f, 0.f}, a11 = {0.f, 0.f};   // q1
    #pragma unroll 4
    for (int h = 0; h < 64; ++h) {
        const uint2 eb = up[(size_t)h * 128];   // h-stride = 512 bf16 = 128 uint2
        const float e0 = __builtin_bit_cast(float, eb.x << 16);
        const float e1 = __builtin_bit_cast(float, eb.x & 0xFFFF0000u);
        const float e2 = __builtin_bit_cast(float, eb.y << 16);
        const float e3 = __builtin_bit_cast(float, eb.y & 0xFFFF0000u);
        const float4 e = s_eav[h0 + h];         // uniform addr -> broadcast
        f32x2 p00 = f32x2{e0, e1} * e.x + 1.0f;
        f32x2 p01 = f32x2{e2, e3} * e.x + 1.0f;
        f32x2 p10 = f32x2{e0, e1} * e.y + 1.0f;
        f32x2 p11 = f32x2{e2, e3} * e.y + 1.0f;
        f32x2 r00 = {__builtin_amdgcn_rcpf(p00.x), __builtin_amdgcn_rcpf(p00.y)};
        f32x2 r01 = {__builtin_amdgcn_rcpf(p01.x), __builtin_amdgcn_rcpf(p01.y)};
        f32x2 r10 = {__builtin_amdgcn_rcpf(p10.x), __builtin_amdgcn_rcpf(p10.y)};
        f32x2 r11 = {__builtin_amdgcn_rcpf(p11.x), __builtin_amdgcn_rcpf(p11.y)};
        a00 += r00 * e.z;
        a01 += r01 * e.z;
        a10 += r10 * e.z;
        a11 += r11 * e.z;
    }
    *(f32x4*)&s_part[hs][0][kq * 4] = f32x4{a00.x, a00.y, a01.x, a01.y};
    *(f32x4*)&s_part[hs][1][kq * 4] = f32x4{a10.x, a10.y, a11.x, a11.y};
    __syncthreads();

    if (t < 512) {
        const int kk = t & 255, qq = t >> 8;
        float z = 0.f;
        #pragma unroll
        for (int j = 0; j < 16; ++j) z += s_part[j][qq][kk];
        zout[(size_t)(bq0 + qq) * 512 + kh * 256 + kk] = -2.0f * z;
    }
}

// ---------------------------------------------------------------------------
// softmax over k: one block per (b,q); writes attn f32 (output) + bf16 (for PV)
__global__ __launch_bounds__(512) void softmax_kernel(
    const float* __restrict__ zin, float* __restrict__ attn_out,
    short* __restrict__ attnb)
{
    __shared__ float s_red[16];
    const int t = threadIdx.x, bqi = blockIdx.x;
    const float z = zin[(size_t)bqi * 512 + t];
    const int lane = t & 63, wid = t >> 6;

    float m = z;
    #pragma unroll
    for (int off = 32; off > 0; off >>= 1)
        m = fmaxf(m, __shfl_xor(m, off, 64));
    if (lane == 0) s_red[wid] = m;
    __syncthreads();
    float mx = s_red[0];
    #pragma unroll
    for (int w = 1; w < 8; ++w) mx = fmaxf(mx, s_red[w]);
    const float p = __expf(z - mx);
    __syncthreads();   // WAR on s_red

    float sl = p;
    #pragma unroll
    for (int off = 32; off > 0; off >>= 1)
        sl += __shfl_xor(sl, off, 64);
    if (lane == 0) s_red[wid] = sl;
    __syncthreads();
    float s = 0.f;
    #pragma unroll
    for (int w = 0; w < 8; ++w) s += s_red[w];

    const float a = p * (1.0f / s);
    attn_out[(size_t)bqi * 512 + t] = a;
    attnb[(size_t)bqi * 512 + t] = (short)f2bf(a);
}

// ---------------------------------------------------------------------------
// PV GEMM: outh[b][128][1024] = attnb[b][128][512] @ valT[b][1024][512]^T
// 128m x 64n tile, K=512 (8 steps); grid b*16+nt = 64 blocks
__global__ __launch_bounds__(256) void pv_gemm(
    const short* __restrict__ attnb, const short* __restrict__ valT,
    float* __restrict__ outh)
{
    __shared__ short ldsA[2][128][64];
    __shared__ short ldsB[2][64][64];
    const int t = threadIdx.x, bx = blockIdx.x;
    const int b = bx >> 4, nt = bx & 15;
    const int n0 = nt * 64;
    const short* A = attnb + (size_t)b * 128 * 512;                    // [128][512]
    const short* B = valT + (size_t)b * 1024 * 512 + (size_t)n0 * 512; // [64][512] tile

    f32x4 acc[4][2];
    #pragma unroll
    for (int i = 0; i < 4; ++i)
        #pragma unroll
        for (int j = 0; j < 2; ++j) acc[i][j] = f32x4{0.f, 0.f, 0.f, 0.f};

    const int lane = t & 63, wid = t >> 6;
    const int wr = wid >> 1, wc = wid & 1;
    const int fr = lane & 15, fko = (lane >> 4) * 16;

    #define STAGE_PV(buf, k0) do {                                              \
        _Pragma("unroll")                                                       \
        for (int it = 0; it < 4; ++it) {                                        \
            const int idx = it * 256 + t;                                       \
            const int row = idx >> 3, c16 = idx & 7;                            \
            const int sc = c16 ^ (row & 7);                                     \
            GLD16(A + (size_t)row * 512 + (k0) + sc * 8,                        \
                  &ldsA[buf][0][0] + idx * 8);                                  \
        }                                                                       \
        _Pragma("unroll")                                                       \
        for (int it = 0; it < 2; ++it) {                                        \
            const int idx = it * 256 + t;                                       \
            const int row = idx >> 3, c16 = idx & 7;                            \
            const int sc = c16 ^ (row & 7);                                     \
            GLD16(B + (size_t)row * 512 + (k0) + sc * 8,                        \
                  &ldsB[buf][0][0] + idx * 8);                                  \
        }                                                                       \
    } while (0)

    #define COMPUTE_PV(buf) do {                                                \
        _Pragma("unroll")                                                       \
        for (int kk = 0; kk < 2; ++kk) {                                        \
            s16x8 af[4], bfv[2];                                                \
            _Pragma("unroll")                                                   \
            for (int i = 0; i < 4; ++i) {                                       \
                const int rowA = wr * 64 + i * 16 + fr;                         \
                int offA = rowA * 128 + kk * 64 + fko; offA ^= (rowA & 7) << 4; \
                af[i] = *(const s16x8*)((const char*)&ldsA[buf][0][0] + offA);  \
            }                                                                   \
            _Pragma("unroll")                                                   \
            for (int ni = 0; ni < 2; ++ni) {                                    \
                const int rowB = wc * 32 + ni * 16 + fr;                        \
                int offB = rowB * 128 + kk * 64 + fko; offB ^= (rowB & 7) << 4; \
                bfv[ni] = *(const s16x8*)((const char*)&ldsB[buf][0][0] + offB);\
            }                                                                   \
            _Pragma("unroll")                                                   \
            for (int mi = 0; mi < 4; ++mi)                                      \
                _Pragma("unroll")                                               \
                for (int ni = 0; ni < 2; ++ni)                                  \
                    acc[mi][ni] = __builtin_amdgcn_mfma_f32_16x16x32_bf16(      \
                                      af[mi], bfv[ni], acc[mi][ni], 0, 0, 0);   \
        }                                                                       \
    } while (0)

    STAGE_PV(0, 0);
    __syncthreads();
    int cur = 0;
    for (int s = 0; s < 7; ++s) {
        STAGE_PV(cur ^ 1, (s + 1) * 64);
        COMPUTE_PV(cur);
        __syncthreads();
        cur ^= 1;
    }
    COMPUTE_PV(cur);

    const int row0 = (lane >> 4) * 4;
    #pragma unroll
    for (int ni = 0; ni < 2; ++ni) {
        const int n = n0 + wc * 32 + ni * 16 + fr;
        #pragma unroll
        for (int mi = 0; mi < 4; ++mi) {
            const int m = wr * 64 + mi * 16 + row0;
            #pragma unroll
            for (int j = 0; j < 4; ++j)
                outh[(size_t)(b * 128 + m + j) * 1024 + n] = acc[mi][ni][j];
        }
    }
    #undef STAGE_PV
    #undef COMPUTE_PV
}

extern "C" void kernel_launch(void* const* d_in, const int* in_sizes, int n_in,
                              void* d_out, int out_size, void* d_ws, size_t ws_size,
                              hipStream_t stream)
{
    const float* query = (const float*)d_in[0];
    const float* key   = (const float*)d_in[1];
    const float* value = (const float*)d_in[2];
    const float* Wq    = (const float*)d_in[3];
    const float* bq    = (const float*)d_in[4];
    const float* Wk    = (const float*)d_in[5];
    const float* v     = (const float*)d_in[6];
    float* out = (float*)d_out;

    // workspace layout (21 MB):
    char* w = (char*)d_ws;
    float*          ws_Ea  = (float*)w;                       // 2 MB
    unsigned short* ws_EbT = (unsigned short*)(w + (2u << 20)); // 4 MB (bf16)
    short* Qb     = (short*)(w + (6u << 20));                 // 1 MB
    short* Kb     = (short*)(w + (7u << 20));                 // 4 MB
    short* WqT    = (short*)(w + (11u << 20));                // 2 MB
    short* WkT    = (short*)(w + (13u << 20));                // 2 MB
    short* valT   = (short*)(w + (15u << 20));                // 4 MB
    short* attnb  = (short*)(w + (19u << 20));                // 0.5 MB
    float* zbuf   = (float*)(w + (20u << 20));                // 1 MB

    float* out_h    = out;                                // [512][1024]
    float* out_attn = out + (size_t)NB * NTQ * NH;        // [512][512]

    prep_kernel   <<<dim3(1664), dim3(256),  0, stream>>>(query, key, Wq, Wk, value,
                                                          Qb, Kb, WqT, WkT, valT);
    mm_kernel     <<<dim3(320),  dim3(256),  0, stream>>>(Qb, Kb, WqT, WkT, bq, ws_Ea, ws_EbT);
    scores_z      <<<dim3(512),  dim3(1024), 0, stream>>>(ws_EbT, ws_Ea, v, zbuf);
    softmax_kernel<<<dim3(512),  dim3(512),  0, stream>>>(zbuf, out_attn, attnb);
    pv_gemm       <<<dim3(64),   dim3(256),  0, stream>>>(attnb, valT, out_h);
}

// Round 15
// 66.760 us; speedup vs baseline: 5.8772x; 1.0536x over previous
//
#include <hip/hip_runtime.h>
#include <hip/hip_bf16.h>

typedef float f32x4 __attribute__((ext_vector_type(4)));
typedef float f32x2 __attribute__((ext_vector_type(2)));
typedef short s16x8 __attribute__((ext_vector_type(8)));
typedef short s16x4 __attribute__((ext_vector_type(4)));

#define NB  4
#define NTQ 128
#define NTK 512
#define NH  1024
#define ECLAMP 3.0e4f   // keeps 4-way u-products < f32 max; tanh delta < 1e-9

__device__ __forceinline__ unsigned short f2bf(float x) {
    unsigned u = __builtin_bit_cast(unsigned, x);
    u += 0x7FFFu + ((u >> 16) & 1u);          // round-to-nearest-even
    return (unsigned short)(u >> 16);
}

#define K2E  2.8853900817779268f   // 2*log2(e): exp2(K2E*x) = e^{2x}

// async global->LDS 16B: linear LDS dest (wave base + lane*16), per-lane global src
#define GLD16(gp, lp) __builtin_amdgcn_global_load_lds( \
    (const __attribute__((address_space(1))) unsigned int*)(gp), \
    (__attribute__((address_space(3))) unsigned int*)(lp), 16, 0, 0)

// ---------------------------------------------------------------------------
// prep: blocks [0,640): bf16 copy Q|K (float4 coalesced).
// blocks [640,1664): 64x64 transpose-convert tiles: Wq->WqT, Wk->WkT, value->valT.
__global__ __launch_bounds__(256) void prep_kernel(
    const float* __restrict__ Q, const float* __restrict__ K,
    const float* __restrict__ Wq, const float* __restrict__ Wk,
    const float* __restrict__ value,
    short* __restrict__ Qb, short* __restrict__ Kb,
    short* __restrict__ WqT, short* __restrict__ WkT, short* __restrict__ valT)
{
    const int t = threadIdx.x, bx = blockIdx.x;
    if (bx < 640) {   // copy region: blocks [0,128) = Q, [128,640) = K
        const float* src; short* dst; size_t base;
        if (bx < 128) { src = Q; dst = Qb; base = (size_t)bx * 4096; }
        else          { src = K; dst = Kb; base = (size_t)(bx - 128) * 4096; }
        #pragma unroll
        for (int i = 0; i < 4; ++i) {
            const size_t off = base + (size_t)(i * 256 + t) * 4;
            const float4 vv = *(const float4*)(src + off);
            s16x4 o = { (short)f2bf(vv.x), (short)f2bf(vv.y),
                        (short)f2bf(vv.z), (short)f2bf(vv.w) };
            *(s16x4*)(dst + off) = o;
        }
        return;
    }
    // transpose region
    __shared__ float tile[64][65];
    const int i = bx - 640;
    const float* src; short* dst; int Cs, Rs, r0, c0;
    if (i < 256)      { src = Wq; dst = WqT; Cs = 1024; Rs = 1024; r0 = (i >> 4) * 64; c0 = (i & 15) * 64; }
    else if (i < 512) { const int j = i - 256; src = Wk; dst = WkT; Cs = 1024; Rs = 1024; r0 = (j >> 4) * 64; c0 = (j & 15) * 64; }
    else {
        const int j = i - 512, b = j >> 7, ti = j & 127;
        src = value + (size_t)b * 512 * 1024; dst = valT + (size_t)b * 1024 * 512;
        Cs = 1024; Rs = 512; r0 = (ti >> 4) * 64; c0 = (ti & 15) * 64;
    }
    {   // load 64x64 f32 tile, coalesced 256B/row
        const int c = (t & 15) * 4;
        #pragma unroll
        for (int it = 0; it < 4; ++it) {
            const int r = (t >> 4) + it * 16;
            const float4 vv = *(const float4*)(src + (size_t)(r0 + r) * Cs + c0 + c);
            tile[r][c + 0] = vv.x; tile[r][c + 1] = vv.y;
            tile[r][c + 2] = vv.z; tile[r][c + 3] = vv.w;
        }
    }
    __syncthreads();
    {   // write transposed: 128B per 16-lane group
        const int r = (t & 15) * 4;
        #pragma unroll
        for (int it = 0; it < 4; ++it) {
            const int c = (t >> 4) + it * 16;
            s16x4 o = { (short)f2bf(tile[r + 0][c]), (short)f2bf(tile[r + 1][c]),
                        (short)f2bf(tile[r + 2][c]), (short)f2bf(tile[r + 3][c]) };
            *(s16x4*)(dst + (size_t)(c0 + c) * Rs + r0 + r) = o;
        }
    }
}

// ---------------------------------------------------------------------------
// main GEMMs with epilogue exp (clamped at ECLAMP): swz blocks [0,64): Ea f32;
// [64,320): EbT[b][h][k] transposed, stored bf16.
// 128m x 64n tile, BK=64, dbuf LDS via global_load_lds, XOR-swizzled (rule #21).
__global__ __launch_bounds__(256) void mm_kernel(
    const short* __restrict__ Qb, const short* __restrict__ Kb,
    const short* __restrict__ WqT, const short* __restrict__ WkT,
    const float* __restrict__ bq,
    float* __restrict__ Ea_out, unsigned short* __restrict__ EbT)
{
    __shared__ short ldsA[2][128][64];   // 32 KB
    __shared__ short ldsB[2][64][64];    // 16 KB
    const int t = threadIdx.x;
    const int bx0 = blockIdx.x;
    const int bx = (bx0 & 7) * 40 + (bx0 >> 3);   // XCD-chunked swizzle
    const bool g1 = bx < 64;
    const short *A, *B; int m0, n0;
    if (g1) { A = Qb; B = WqT; m0 = (bx >> 4) * 128; n0 = (bx & 15) * 64; }
    else    { const int i = bx - 64; A = Kb; B = WkT; m0 = (i >> 4) * 128; n0 = (i & 15) * 64; }
    A += (size_t)m0 * 1024; B += (size_t)n0 * 1024;

    f32x4 acc[4][2];
    #pragma unroll
    for (int i = 0; i < 4; ++i)
        #pragma unroll
        for (int j = 0; j < 2; ++j) acc[i][j] = f32x4{0.f, 0.f, 0.f, 0.f};

    const int lane = t & 63, wid = t >> 6;
    const int wr = wid >> 1, wc = wid & 1;          // waves 2x2 over (64m,32n)
    const int fr = lane & 15, fko = (lane >> 4) * 16;   // byte offset in 128B row

    #define STAGE_MM(buf, k0) do {                                              \
        _Pragma("unroll")                                                       \
        for (int it = 0; it < 4; ++it) {                                        \
            const int idx = it * 256 + t;                                       \
            const int row = idx >> 3, c16 = idx & 7;                            \
            const int sc = c16 ^ (row & 7);                                     \
            GLD16(A + (size_t)row * 1024 + (k0) + sc * 8,                       \
                  &ldsA[buf][0][0] + idx * 8);                                  \
        }                                                                       \
        _Pragma("unroll")                                                       \
        for (int it = 0; it < 2; ++it) {                                        \
            const int idx = it * 256 + t;                                       \
            const int row = idx >> 3, c16 = idx & 7;                            \
            const int sc = c16 ^ (row & 7);                                     \
            GLD16(B + (size_t)row * 1024 + (k0) + sc * 8,                       \
                  &ldsB[buf][0][0] + idx * 8);                                  \
        }                                                                       \
    } while (0)

    #define COMPUTE_MM(buf) do {                                                \
        _Pragma("unroll")                                                       \
        for (int kk = 0; kk < 2; ++kk) {                                        \
            s16x8 af[4], bfv[2];                                                \
            _Pragma("unroll")                                                   \
            for (int i = 0; i < 4; ++i) {                                       \
                const int rowA = wr * 64 + i * 16 + fr;                         \
                int offA = rowA * 128 + kk * 64 + fko; offA ^= (rowA & 7) << 4; \
                af[i] = *(const s16x8*)((const char*)&ldsA[buf][0][0] + offA);  \
            }                                                                   \
            _Pragma("unroll")                                                   \
            for (int ni = 0; ni < 2; ++ni) {                                    \
                const int rowB = wc * 32 + ni * 16 + fr;                        \
                int offB = rowB * 128 + kk * 64 + fko; offB ^= (rowB & 7) << 4; \
                bfv[ni] = *(const s16x8*)((const char*)&ldsB[buf][0][0] + offB);\
            }                                                                   \
            _Pragma("unroll")                                                   \
            for (int mi = 0; mi < 4; ++mi)                                      \
                _Pragma("unroll")                                               \
                for (int ni = 0; ni < 2; ++ni)                                  \
                    acc[mi][ni] = __builtin_amdgcn_mfma_f32_16x16x32_bf16(      \
                                      af[mi], bfv[ni], acc[mi][ni], 0, 0, 0);   \
        }                                                                       \
    } while (0)

    STAGE_MM(0, 0);
    __syncthreads();
    int cur = 0;
    for (int s = 0; s < 15; ++s) {
        STAGE_MM(cur ^ 1, (s + 1) * 64);
        COMPUTE_MM(cur);
        __syncthreads();
        cur ^= 1;
    }
    COMPUTE_MM(cur);

    // D layout: col = lane&15, row = (lane>>4)*4 + reg
    const int row0 = (lane >> 4) * 4;
    if (g1) {
        #pragma unroll
        for (int ni = 0; ni < 2; ++ni) {
            const int n = n0 + wc * 32 + ni * 16 + fr;
            const float bias = bq[n];
            #pragma unroll
            for (int mi = 0; mi < 4; ++mi) {
                const int m = m0 + wr * 64 + mi * 16 + row0;
                #pragma unroll
                for (int j = 0; j < 4; ++j)
                    Ea_out[(size_t)(m + j) * 1024 + n] =
                        fminf(__builtin_amdgcn_exp2f(K2E * (acc[mi][ni][j] + bias)), ECLAMP);
            }
        }
    } else {
        #pragma unroll
        for (int mi = 0; mi < 4; ++mi) {
            const int m = m0 + wr * 64 + mi * 16 + row0;
            const int b = m >> 9, kk = m & 511;
            #pragma unroll
            for (int ni = 0; ni < 2; ++ni) {
                const int n = n0 + wc * 32 + ni * 16 + fr;
                s16x4 ev;
                #pragma unroll
                for (int j = 0; j < 4; ++j)
                    ev[j] = (short)f2bf(fminf(__builtin_amdgcn_exp2f(K2E * acc[mi][ni][j]), ECLAMP));
                *(s16x4*)&EbT[((size_t)b * 1024 + n) * 512 + kk] = ev;
            }
        }
    }
    #undef STAGE_MM
    #undef COMPUTE_MM
}

// ---------------------------------------------------------------------------
// scores: z[bq][k] = -2 * sum_h v[h] * rcp(1 + Ea[bq][h]*Eb[b][h][k])
// 4-way h-combine: sum_{i<4} v_i/u_i = (n01*d23 + n23*d01) * rcp(d01*d23)
// -> 1 rcp + 14 VALU per (q,k,4h): trans ops cut 4x (268M -> 67M).
// grid 512, XCD-pinned combo = bid&7; 1024 thr = kq(64) x h-slice(16).
__global__ __launch_bounds__(1024, 8) void scores_z(
    const unsigned short* __restrict__ EbT, const float* __restrict__ Ea,
    const float* __restrict__ v, float* __restrict__ zout)
{
    __shared__ float4 s_eav[1024];        // {Ea_q0[h], Ea_q1[h], v[h], -} 16 KB
    __shared__ float  s_part[16][2][256]; // [hs][q][k-in-half] partials, 32 KB
    const int t = threadIdx.x, bx = blockIdx.x;
    const int combo = bx & 7;             // XCD id: (b, k-half)
    const int b  = combo >> 1, kh = combo & 1;
    const int q2 = bx >> 3;               // 0..63
    const int bq0 = b * 128 + q2 * 2;
    const int kq = t & 63;                // k-quad: k_local = 4kq..4kq+3
    const int hs = t >> 6;                // h-slice (uniform per wave)

    s_eav[t] = make_float4(Ea[(size_t)(bq0 + 0) * 1024 + t],
                           Ea[(size_t)(bq0 + 1) * 1024 + t],
                           v[t], 0.f);
    __syncthreads();

    const int h0 = hs * 64;
    const uint2* up = (const uint2*)(EbT + ((size_t)(b * 1024 + h0)) * 512
                                     + kh * 256 + kq * 4);
    float a00 = 0.f, a01 = 0.f, a02 = 0.f, a03 = 0.f;   // q0, k0..k3
    float a10 = 0.f, a11 = 0.f, a12 = 0.f, a13 = 0.f;   // q1
    #pragma unroll 2
    for (int hg = 0; hg < 16; ++hg) {     // 4-h groups
        const int hb = hg * 4;
        const uint2 r0 = up[(size_t)(hb + 0) * 128];   // h-stride = 128 uint2
        const uint2 r1 = up[(size_t)(hb + 1) * 128];
        const uint2 r2 = up[(size_t)(hb + 2) * 128];
        const uint2 r3 = up[(size_t)(hb + 3) * 128];
        const float4 ev0 = s_eav[h0 + hb + 0];
        const float4 ev1 = s_eav[h0 + hb + 1];
        const float4 ev2 = s_eav[h0 + hb + 2];
        const float4 ev3 = s_eav[h0 + hb + 3];
        float eb0[4], eb1[4], eb2[4], eb3[4];
        eb0[0] = __builtin_bit_cast(float, r0.x << 16);
        eb0[1] = __builtin_bit_cast(float, r0.x & 0xFFFF0000u);
        eb0[2] = __builtin_bit_cast(float, r0.y << 16);
        eb0[3] = __builtin_bit_cast(float, r0.y & 0xFFFF0000u);
        eb1[0] = __builtin_bit_cast(float, r1.x << 16);
        eb1[1] = __builtin_bit_cast(float, r1.x & 0xFFFF0000u);
        eb1[2] = __builtin_bit_cast(float, r1.y << 16);
        eb1[3] = __builtin_bit_cast(float, r1.y & 0xFFFF0000u);
        eb2[0] = __builtin_bit_cast(float, r2.x << 16);
        eb2[1] = __builtin_bit_cast(float, r2.x & 0xFFFF0000u);
        eb2[2] = __builtin_bit_cast(float, r2.y << 16);
        eb2[3] = __builtin_bit_cast(float, r2.y & 0xFFFF0000u);
        eb3[0] = __builtin_bit_cast(float, r3.x << 16);
        eb3[1] = __builtin_bit_cast(float, r3.x & 0xFFFF0000u);
        eb3[2] = __builtin_bit_cast(float, r3.y << 16);
        eb3[3] = __builtin_bit_cast(float, r3.y & 0xFFFF0000u);

        #define GRP4(accv, ea0, ea1, ea2, ea3, kk) do {                         \
            const float u0 = __builtin_fmaf(ea0, eb0[kk], 1.0f);                \
            const float u1 = __builtin_fmaf(ea1, eb1[kk], 1.0f);                \
            const float u2 = __builtin_fmaf(ea2, eb2[kk], 1.0f);                \
            const float u3 = __builtin_fmaf(ea3, eb3[kk], 1.0f);                \
            const float d01 = u0 * u1, d23 = u2 * u3;                           \
            float n01 = ev0.z * u1; n01 = __builtin_fmaf(ev1.z, u0, n01);       \
            float n23 = ev2.z * u3; n23 = __builtin_fmaf(ev3.z, u2, n23);       \
            float n = n01 * d23; n = __builtin_fmaf(n23, d01, n);               \
            const float r = __builtin_amdgcn_rcpf(d01 * d23);                   \
            accv = __builtin_fmaf(n, r, accv);                                  \
        } while (0)

        GRP4(a00, ev0.x, ev1.x, ev2.x, ev3.x, 0);
        GRP4(a01, ev0.x, ev1.x, ev2.x, ev3.x, 1);
        GRP4(a02, ev0.x, ev1.x, ev2.x, ev3.x, 2);
        GRP4(a03, ev0.x, ev1.x, ev2.x, ev3.x, 3);
        GRP4(a10, ev0.y, ev1.y, ev2.y, ev3.y, 0);
        GRP4(a11, ev0.y, ev1.y, ev2.y, ev3.y, 1);
        GRP4(a12, ev0.y, ev1.y, ev2.y, ev3.y, 2);
        GRP4(a13, ev0.y, ev1.y, ev2.y, ev3.y, 3);
        #undef GRP4
    }
    *(f32x4*)&s_part[hs][0][kq * 4] = f32x4{a00, a01, a02, a03};
    *(f32x4*)&s_part[hs][1][kq * 4] = f32x4{a10, a11, a12, a13};
    __syncthreads();

    if (t < 512) {
        const int kk = t & 255, qq = t >> 8;
        float z = 0.f;
        #pragma unroll
        for (int j = 0; j < 16; ++j) z += s_part[j][qq][kk];
        zout[(size_t)(bq0 + qq) * 512 + kh * 256 + kk] = -2.0f * z;
    }
}

// ---------------------------------------------------------------------------
// softmax over k: one block per (b,q); writes attn f32 (output) + bf16 (for PV)
__global__ __launch_bounds__(512) void softmax_kernel(
    const float* __restrict__ zin, float* __restrict__ attn_out,
    short* __restrict__ attnb)
{
    __shared__ float s_red[16];
    const int t = threadIdx.x, bqi = blockIdx.x;
    const float z = zin[(size_t)bqi * 512 + t];
    const int lane = t & 63, wid = t >> 6;

    float m = z;
    #pragma unroll
    for (int off = 32; off > 0; off >>= 1)
        m = fmaxf(m, __shfl_xor(m, off, 64));
    if (lane == 0) s_red[wid] = m;
    __syncthreads();
    float mx = s_red[0];
    #pragma unroll
    for (int w = 1; w < 8; ++w) mx = fmaxf(mx, s_red[w]);
    const float p = __expf(z - mx);
    __syncthreads();   // WAR on s_red

    float sl = p;
    #pragma unroll
    for (int off = 32; off > 0; off >>= 1)
        sl += __shfl_xor(sl, off, 64);
    if (lane == 0) s_red[wid] = sl;
    __syncthreads();
    float s = 0.f;
    #pragma unroll
    for (int w = 0; w < 8; ++w) s += s_red[w];

    const float a = p * (1.0f / s);
    attn_out[(size_t)bqi * 512 + t] = a;
    attnb[(size_t)bqi * 512 + t] = (short)f2bf(a);
}

// ---------------------------------------------------------------------------
// PV GEMM: outh[b][128][1024] = attnb[b][128][512] @ valT[b][1024][512]^T
// 128m x 64n tile, K=512 (8 steps); grid b*16+nt = 64 blocks
__global__ __launch_bounds__(256) void pv_gemm(
    const short* __restrict__ attnb, const short* __restrict__ valT,
    float* __restrict__ outh)
{
    __shared__ short ldsA[2][128][64];
    __shared__ short ldsB[2][64][64];
    const int t = threadIdx.x, bx = blockIdx.x;
    const int b = bx >> 4, nt = bx & 15;
    const int n0 = nt * 64;
    const short* A = attnb + (size_t)b * 128 * 512;                    // [128][512]
    const short* B = valT + (size_t)b * 1024 * 512 + (size_t)n0 * 512; // [64][512] tile

    f32x4 acc[4][2];
    #pragma unroll
    for (int i = 0; i < 4; ++i)
        #pragma unroll
        for (int j = 0; j < 2; ++j) acc[i][j] = f32x4{0.f, 0.f, 0.f, 0.f};

    const int lane = t & 63, wid = t >> 6;
    const int wr = wid >> 1, wc = wid & 1;
    const int fr = lane & 15, fko = (lane >> 4) * 16;

    #define STAGE_PV(buf, k0) do {                                              \
        _Pragma("unroll")                                                       \
        for (int it = 0; it < 4; ++it) {                                        \
            const int idx = it * 256 + t;                                       \
            const int row = idx >> 3, c16 = idx & 7;                            \
            const int sc = c16 ^ (row & 7);                                     \
            GLD16(A + (size_t)row * 512 + (k0) + sc * 8,                        \
                  &ldsA[buf][0][0] + idx * 8);                                  \
        }                                                                       \
        _Pragma("unroll")                                                       \
        for (int it = 0; it < 2; ++it) {                                        \
            const int idx = it * 256 + t;                                       \
            const int row = idx >> 3, c16 = idx & 7;                            \
            const int sc = c16 ^ (row & 7);                                     \
            GLD16(B + (size_t)row * 512 + (k0) + sc * 8,                        \
                  &ldsB[buf][0][0] + idx * 8);                                  \
        }                                                                       \
    } while (0)

    #define COMPUTE_PV(buf) do {                                                \
        _Pragma("unroll")                                                       \
        for (int kk = 0; kk < 2; ++kk) {                                        \
            s16x8 af[4], bfv[2];                                                \
            _Pragma("unroll")                                                   \
            for (int i = 0; i < 4; ++i) {                                       \
                const int rowA = wr * 64 + i * 16 + fr;                         \
                int offA = rowA * 128 + kk * 64 + fko; offA ^= (rowA & 7) << 4; \
                af[i] = *(const s16x8*)((const char*)&ldsA[buf][0][0] + offA);  \
            }                                                                   \
            _Pragma("unroll")                                                   \
            for (int ni = 0; ni < 2; ++ni) {                                    \
                const int rowB = wc * 32 + ni * 16 + fr;                        \
                int offB = rowB * 128 + kk * 64 + fko; offB ^= (rowB & 7) << 4; \
                bfv[ni] = *(const s16x8*)((const char*)&ldsB[buf][0][0] + offB);\
            }                                                                   \
            _Pragma("unroll")                                                   \
            for (int mi = 0; mi < 4; ++mi)                                      \
                _Pragma("unroll")                                               \
                for (int ni = 0; ni < 2; ++ni)                                  \
                    acc[mi][ni] = __builtin_amdgcn_mfma_f32_16x16x32_bf16(      \
                                      af[mi], bfv[ni], acc[mi][ni], 0, 0, 0);   \
        }                                                                       \
    } while (0)

    STAGE_PV(0, 0);
    __syncthreads();
    int cur = 0;
    for (int s = 0; s < 7; ++s) {
        STAGE_PV(cur ^ 1, (s + 1) * 64);
        COMPUTE_PV(cur);
        __syncthreads();
        cur ^= 1;
    }
    COMPUTE_PV(cur);

    const int row0 = (lane >> 4) * 4;
    #pragma unroll
    for (int ni = 0; ni < 2; ++ni) {
        const int n = n0 + wc * 32 + ni * 16 + fr;
        #pragma unroll
        for (int mi = 0; mi < 4; ++mi) {
            const int m = wr * 64 + mi * 16 + row0;
            #pragma unroll
            for (int j = 0; j < 4; ++j)
                outh[(size_t)(b * 128 + m + j) * 1024 + n] = acc[mi][ni][j];
        }
    }
    #undef STAGE_PV
    #undef COMPUTE_PV
}

extern "C" void kernel_launch(void* const* d_in, const int* in_sizes, int n_in,
                              void* d_out, int out_size, void* d_ws, size_t ws_size,
                              hipStream_t stream)
{
    const float* query = (const float*)d_in[0];
    const float* key   = (const float*)d_in[1];
    const float* value = (const float*)d_in[2];
    const float* Wq    = (const float*)d_in[3];
    const float* bq    = (const float*)d_in[4];
    const float* Wk    = (const float*)d_in[5];
    const float* v     = (const float*)d_in[6];
    float* out = (float*)d_out;

    // workspace layout (21 MB):
    char* w = (char*)d_ws;
    float*          ws_Ea  = (float*)w;                       // 2 MB
    unsigned short* ws_EbT = (unsigned short*)(w + (2u << 20)); // 4 MB (bf16)
    short* Qb     = (short*)(w + (6u << 20));                 // 1 MB
    short* Kb     = (short*)(w + (7u << 20));                 // 4 MB
    short* WqT    = (short*)(w + (11u << 20));                // 2 MB
    short* WkT    = (short*)(w + (13u << 20));                // 2 MB
    short* valT   = (short*)(w + (15u << 20));                // 4 MB
    short* attnb  = (short*)(w + (19u << 20));                // 0.5 MB
    float* zbuf   = (float*)(w + (20u << 20));                // 1 MB

    float* out_h    = out;                                // [512][1024]
    float* out_attn = out + (size_t)NB * NTQ * NH;        // [512][512]

    prep_kernel   <<<dim3(1664), dim3(256),  0, stream>>>(query, key, Wq, Wk, value,
                                                          Qb, Kb, WqT, WkT, valT);
    mm_kernel     <<<dim3(320),  dim3(256),  0, stream>>>(Qb, Kb, WqT, WkT, bq, ws_Ea, ws_EbT);
    scores_z      <<<dim3(512),  dim3(1024), 0, stream>>>(ws_EbT, ws_Ea, v, zbuf);
    softmax_kernel<<<dim3(512),  dim3(512),  0, stream>>>(zbuf, out_attn, attnb);
    pv_gemm       <<<dim3(64),   dim3(256),  0, stream>>>(attnb, valT, out_h);
}

// Round 16
// 65.922 us; speedup vs baseline: 5.9519x; 1.0127x over previous
//
#include <hip/hip_runtime.h>
#include <hip/hip_bf16.h>

typedef float f32x4 __attribute__((ext_vector_type(4)));
typedef float f32x2 __attribute__((ext_vector_type(2)));
typedef short s16x8 __attribute__((ext_vector_type(8)));
typedef short s16x4 __attribute__((ext_vector_type(4)));

#define NB  4
#define NTQ 128
#define NTK 512
#define NH  1024
#define ECLAMP 3.0e4f   // keeps 4-way u-products < f32 max; tanh delta < 1e-9

__device__ __forceinline__ unsigned short f2bf(float x) {
    unsigned u = __builtin_bit_cast(unsigned, x);
    u += 0x7FFFu + ((u >> 16) & 1u);          // round-to-nearest-even
    return (unsigned short)(u >> 16);
}

#define K2E  2.8853900817779268f   // 2*log2(e): exp2(K2E*x) = e^{2x}

// async global->LDS 16B: linear LDS dest (wave base + lane*16), per-lane global src
#define GLD16(gp, lp) __builtin_amdgcn_global_load_lds( \
    (const __attribute__((address_space(1))) unsigned int*)(gp), \
    (__attribute__((address_space(3))) unsigned int*)(lp), 16, 0, 0)

// ---------------------------------------------------------------------------
// prep: blocks [0,640): bf16 copy Q|K (float4 coalesced).
// blocks [640,1664): 64x64 transpose-convert tiles: Wq->WqT, Wk->WkT, value->valT.
__global__ __launch_bounds__(256) void prep_kernel(
    const float* __restrict__ Q, const float* __restrict__ K,
    const float* __restrict__ Wq, const float* __restrict__ Wk,
    const float* __restrict__ value,
    short* __restrict__ Qb, short* __restrict__ Kb,
    short* __restrict__ WqT, short* __restrict__ WkT, short* __restrict__ valT)
{
    const int t = threadIdx.x, bx = blockIdx.x;
    if (bx < 640) {   // copy region: blocks [0,128) = Q, [128,640) = K
        const float* src; short* dst; size_t base;
        if (bx < 128) { src = Q; dst = Qb; base = (size_t)bx * 4096; }
        else          { src = K; dst = Kb; base = (size_t)(bx - 128) * 4096; }
        #pragma unroll
        for (int i = 0; i < 4; ++i) {
            const size_t off = base + (size_t)(i * 256 + t) * 4;
            const float4 vv = *(const float4*)(src + off);
            s16x4 o = { (short)f2bf(vv.x), (short)f2bf(vv.y),
                        (short)f2bf(vv.z), (short)f2bf(vv.w) };
            *(s16x4*)(dst + off) = o;
        }
        return;
    }
    // transpose region
    __shared__ float tile[64][65];
    const int i = bx - 640;
    const float* src; short* dst; int Cs, Rs, r0, c0;
    if (i < 256)      { src = Wq; dst = WqT; Cs = 1024; Rs = 1024; r0 = (i >> 4) * 64; c0 = (i & 15) * 64; }
    else if (i < 512) { const int j = i - 256; src = Wk; dst = WkT; Cs = 1024; Rs = 1024; r0 = (j >> 4) * 64; c0 = (j & 15) * 64; }
    else {
        const int j = i - 512, b = j >> 7, ti = j & 127;
        src = value + (size_t)b * 512 * 1024; dst = valT + (size_t)b * 1024 * 512;
        Cs = 1024; Rs = 512; r0 = (ti >> 4) * 64; c0 = (ti & 15) * 64;
    }
    {   // load 64x64 f32 tile, coalesced 256B/row
        const int c = (t & 15) * 4;
        #pragma unroll
        for (int it = 0; it < 4; ++it) {
            const int r = (t >> 4) + it * 16;
            const float4 vv = *(const float4*)(src + (size_t)(r0 + r) * Cs + c0 + c);
            tile[r][c + 0] = vv.x; tile[r][c + 1] = vv.y;
            tile[r][c + 2] = vv.z; tile[r][c + 3] = vv.w;
        }
    }
    __syncthreads();
    {   // write transposed: 128B per 16-lane group
        const int r = (t & 15) * 4;
        #pragma unroll
        for (int it = 0; it < 4; ++it) {
            const int c = (t >> 4) + it * 16;
            s16x4 o = { (short)f2bf(tile[r + 0][c]), (short)f2bf(tile[r + 1][c]),
                        (short)f2bf(tile[r + 2][c]), (short)f2bf(tile[r + 3][c]) };
            *(s16x4*)(dst + (size_t)(c0 + c) * Rs + r0 + r) = o;
        }
    }
}

// ---------------------------------------------------------------------------
// main GEMMs with epilogue exp (clamped at ECLAMP): swz blocks [0,64): Ea f32;
// [64,320): EbT[b][h][k] transposed, stored bf16.
// 128m x 64n tile, BK=64, dbuf LDS via global_load_lds, XOR-swizzled (rule #21).
__global__ __launch_bounds__(256) void mm_kernel(
    const short* __restrict__ Qb, const short* __restrict__ Kb,
    const short* __restrict__ WqT, const short* __restrict__ WkT,
    const float* __restrict__ bq,
    float* __restrict__ Ea_out, unsigned short* __restrict__ EbT)
{
    __shared__ short ldsA[2][128][64];   // 32 KB
    __shared__ short ldsB[2][64][64];    // 16 KB
    const int t = threadIdx.x;
    const int bx0 = blockIdx.x;
    const int bx = (bx0 & 7) * 40 + (bx0 >> 3);   // XCD-chunked swizzle
    const bool g1 = bx < 64;
    const short *A, *B; int m0, n0;
    if (g1) { A = Qb; B = WqT; m0 = (bx >> 4) * 128; n0 = (bx & 15) * 64; }
    else    { const int i = bx - 64; A = Kb; B = WkT; m0 = (i >> 4) * 128; n0 = (i & 15) * 64; }
    A += (size_t)m0 * 1024; B += (size_t)n0 * 1024;

    f32x4 acc[4][2];
    #pragma unroll
    for (int i = 0; i < 4; ++i)
        #pragma unroll
        for (int j = 0; j < 2; ++j) acc[i][j] = f32x4{0.f, 0.f, 0.f, 0.f};

    const int lane = t & 63, wid = t >> 6;
    const int wr = wid >> 1, wc = wid & 1;          // waves 2x2 over (64m,32n)
    const int fr = lane & 15, fko = (lane >> 4) * 16;   // byte offset in 128B row

    #define STAGE_MM(buf, k0) do {                                              \
        _Pragma("unroll")                                                       \
        for (int it = 0; it < 4; ++it) {                                        \
            const int idx = it * 256 + t;                                       \
            const int row = idx >> 3, c16 = idx & 7;                            \
            const int sc = c16 ^ (row & 7);                                     \
            GLD16(A + (size_t)row * 1024 + (k0) + sc * 8,                       \
                  &ldsA[buf][0][0] + idx * 8);                                  \
        }                                                                       \
        _Pragma("unroll")                                                       \
        for (int it = 0; it < 2; ++it) {                                        \
            const int idx = it * 256 + t;                                       \
            const int row = idx >> 3, c16 = idx & 7;                            \
            const int sc = c16 ^ (row & 7);                                     \
            GLD16(B + (size_t)row * 1024 + (k0) + sc * 8,                       \
                  &ldsB[buf][0][0] + idx * 8);                                  \
        }                                                                       \
    } while (0)

    #define COMPUTE_MM(buf) do {                                                \
        _Pragma("unroll")                                                       \
        for (int kk = 0; kk < 2; ++kk) {                                        \
            s16x8 af[4], bfv[2];                                                \
            _Pragma("unroll")                                                   \
            for (int i = 0; i < 4; ++i) {                                       \
                const int rowA = wr * 64 + i * 16 + fr;                         \
                int offA = rowA * 128 + kk * 64 + fko; offA ^= (rowA & 7) << 4; \
                af[i] = *(const s16x8*)((const char*)&ldsA[buf][0][0] + offA);  \
            }                                                                   \
            _Pragma("unroll")                                                   \
            for (int ni = 0; ni < 2; ++ni) {                                    \
                const int rowB = wc * 32 + ni * 16 + fr;                        \
                int offB = rowB * 128 + kk * 64 + fko; offB ^= (rowB & 7) << 4; \
                bfv[ni] = *(const s16x8*)((const char*)&ldsB[buf][0][0] + offB);\
            }                                                                   \
            _Pragma("unroll")                                                   \
            for (int mi = 0; mi < 4; ++mi)                                      \
                _Pragma("unroll")                                               \
                for (int ni = 0; ni < 2; ++ni)                                  \
                    acc[mi][ni] = __builtin_amdgcn_mfma_f32_16x16x32_bf16(      \
                                      af[mi], bfv[ni], acc[mi][ni], 0, 0, 0);   \
        }                                                                       \
    } while (0)

    STAGE_MM(0, 0);
    __syncthreads();
    int cur = 0;
    for (int s = 0; s < 15; ++s) {
        STAGE_MM(cur ^ 1, (s + 1) * 64);
        COMPUTE_MM(cur);
        __syncthreads();
        cur ^= 1;
    }
    COMPUTE_MM(cur);

    // D layout: col = lane&15, row = (lane>>4)*4 + reg
    const int row0 = (lane >> 4) * 4;
    if (g1) {
        #pragma unroll
        for (int ni = 0; ni < 2; ++ni) {
            const int n = n0 + wc * 32 + ni * 16 + fr;
            const float bias = bq[n];
            #pragma unroll
            for (int mi = 0; mi < 4; ++mi) {
                const int m = m0 + wr * 64 + mi * 16 + row0;
                #pragma unroll
                for (int j = 0; j < 4; ++j)
                    Ea_out[(size_t)(m + j) * 1024 + n] =
                        fminf(__builtin_amdgcn_exp2f(K2E * (acc[mi][ni][j] + bias)), ECLAMP);
            }
        }
    } else {
        #pragma unroll
        for (int mi = 0; mi < 4; ++mi) {
            const int m = m0 + wr * 64 + mi * 16 + row0;
            const int b = m >> 9, kk = m & 511;
            #pragma unroll
            for (int ni = 0; ni < 2; ++ni) {
                const int n = n0 + wc * 32 + ni * 16 + fr;
                s16x4 ev;
                #pragma unroll
                for (int j = 0; j < 4; ++j)
                    ev[j] = (short)f2bf(fminf(__builtin_amdgcn_exp2f(K2E * acc[mi][ni][j]), ECLAMP));
                *(s16x4*)&EbT[((size_t)b * 1024 + n) * 512 + kk] = ev;
            }
        }
    }
    #undef STAGE_MM
    #undef COMPUTE_MM
}

// ---------------------------------------------------------------------------
// fused scores+softmax: block = (b, q-pair), 256 blocks x 1024 thr =
// kq(128, full k) x hs(8). 4-way h-combine (1 rcp + 14 VALU per q,k,4h).
// Partials via 32KB LDS; in-block softmax; writes attn f32 + bf16.
// b = bx&3 -> each XCD's blocks touch one batch (EbT[b] = 1MB, L2-resident).
__global__ __launch_bounds__(1024, 4) void scores_softmax(
    const unsigned short* __restrict__ EbT, const float* __restrict__ Ea,
    const float* __restrict__ v,
    float* __restrict__ attn_out, short* __restrict__ attnb)
{
    __shared__ float4 s_eav[1024];       // {Ea_q0[h], Ea_q1[h], v[h], -} 16 KB
    __shared__ float  s_part[8][2][512]; // [hs][q][k] partials, 32 KB
    __shared__ float  s_red[16];
    const int t = threadIdx.x, bx = blockIdx.x;
    const int b = bx & 3;                // batch pinned per XCD pair
    const int q2 = bx >> 2;              // 0..63
    const int bq0 = b * 128 + q2 * 2;
    const int kq = t & 127;              // k-quad: k = 4kq..4kq+3 (full 512)
    const int hs = t >> 7;               // 8 h-slices of 128
    const int lane = t & 63, wid = t >> 6;

    s_eav[t] = make_float4(Ea[(size_t)(bq0 + 0) * 1024 + t],
                           Ea[(size_t)(bq0 + 1) * 1024 + t],
                           v[t], 0.f);
    __syncthreads();

    const int h0 = hs * 128;
    const uint2* up = (const uint2*)(EbT + ((size_t)(b * 1024 + h0)) * 512) + kq;
    float a00 = 0.f, a01 = 0.f, a02 = 0.f, a03 = 0.f;   // q0, k0..k3
    float a10 = 0.f, a11 = 0.f, a12 = 0.f, a13 = 0.f;   // q1
    #pragma unroll 2
    for (int hg = 0; hg < 32; ++hg) {    // 4-h groups (128 h per slice)
        const int hb = hg * 4;
        const uint2 r0 = up[(size_t)(hb + 0) * 128];   // h-stride = 128 uint2
        const uint2 r1 = up[(size_t)(hb + 1) * 128];
        const uint2 r2 = up[(size_t)(hb + 2) * 128];
        const uint2 r3 = up[(size_t)(hb + 3) * 128];
        const float4 ev0 = s_eav[h0 + hb + 0];
        const float4 ev1 = s_eav[h0 + hb + 1];
        const float4 ev2 = s_eav[h0 + hb + 2];
        const float4 ev3 = s_eav[h0 + hb + 3];
        float eb0[4], eb1[4], eb2[4], eb3[4];
        eb0[0] = __builtin_bit_cast(float, r0.x << 16);
        eb0[1] = __builtin_bit_cast(float, r0.x & 0xFFFF0000u);
        eb0[2] = __builtin_bit_cast(float, r0.y << 16);
        eb0[3] = __builtin_bit_cast(float, r0.y & 0xFFFF0000u);
        eb1[0] = __builtin_bit_cast(float, r1.x << 16);
        eb1[1] = __builtin_bit_cast(float, r1.x & 0xFFFF0000u);
        eb1[2] = __builtin_bit_cast(float, r1.y << 16);
        eb1[3] = __builtin_bit_cast(float, r1.y & 0xFFFF0000u);
        eb2[0] = __builtin_bit_cast(float, r2.x << 16);
        eb2[1] = __builtin_bit_cast(float, r2.x & 0xFFFF0000u);
        eb2[2] = __builtin_bit_cast(float, r2.y << 16);
        eb2[3] = __builtin_bit_cast(float, r2.y & 0xFFFF0000u);
        eb3[0] = __builtin_bit_cast(float, r3.x << 16);
        eb3[1] = __builtin_bit_cast(float, r3.x & 0xFFFF0000u);
        eb3[2] = __builtin_bit_cast(float, r3.y << 16);
        eb3[3] = __builtin_bit_cast(float, r3.y & 0xFFFF0000u);

        #define GRP4(accv, ea0, ea1, ea2, ea3, kk) do {                         \
            const float u0 = __builtin_fmaf(ea0, eb0[kk], 1.0f);                \
            const float u1 = __builtin_fmaf(ea1, eb1[kk], 1.0f);                \
            const float u2 = __builtin_fmaf(ea2, eb2[kk], 1.0f);                \
            const float u3 = __builtin_fmaf(ea3, eb3[kk], 1.0f);                \
            const float d01 = u0 * u1, d23 = u2 * u3;                           \
            float n01 = ev0.z * u1; n01 = __builtin_fmaf(ev1.z, u0, n01);       \
            float n23 = ev2.z * u3; n23 = __builtin_fmaf(ev3.z, u2, n23);       \
            float n = n01 * d23; n = __builtin_fmaf(n23, d01, n);               \
            const float r = __builtin_amdgcn_rcpf(d01 * d23);                   \
            accv = __builtin_fmaf(n, r, accv);                                  \
        } while (0)

        GRP4(a00, ev0.x, ev1.x, ev2.x, ev3.x, 0);
        GRP4(a01, ev0.x, ev1.x, ev2.x, ev3.x, 1);
        GRP4(a02, ev0.x, ev1.x, ev2.x, ev3.x, 2);
        GRP4(a03, ev0.x, ev1.x, ev2.x, ev3.x, 3);
        GRP4(a10, ev0.y, ev1.y, ev2.y, ev3.y, 0);
        GRP4(a11, ev0.y, ev1.y, ev2.y, ev3.y, 1);
        GRP4(a12, ev0.y, ev1.y, ev2.y, ev3.y, 2);
        GRP4(a13, ev0.y, ev1.y, ev2.y, ev3.y, 3);
        #undef GRP4
    }
    *(f32x4*)&s_part[hs][0][kq * 4] = f32x4{a00, a01, a02, a03};
    *(f32x4*)&s_part[hs][1][kq * 4] = f32x4{a10, a11, a12, a13};
    __syncthreads();

    // combine + softmax: thread t -> (qq = t>>9, kk = t&511)
    const int kk = t & 511, qq = t >> 9;
    float z = 0.f;
    #pragma unroll
    for (int j = 0; j < 8; ++j) z += s_part[j][qq][kk];
    z *= -2.0f;

    // per-q max (waves 0-7 = q0, waves 8-15 = q1)
    float m = z;
    #pragma unroll
    for (int off = 32; off > 0; off >>= 1)
        m = fmaxf(m, __shfl_xor(m, off, 64));
    if (lane == 0) s_red[wid] = m;
    __syncthreads();
    float mx = s_red[qq * 8];
    #pragma unroll
    for (int w = 1; w < 8; ++w) mx = fmaxf(mx, s_red[qq * 8 + w]);
    const float p = __expf(z - mx);
    __syncthreads();   // WAR on s_red

    // per-q sum
    float sl = p;
    #pragma unroll
    for (int off = 32; off > 0; off >>= 1)
        sl += __shfl_xor(sl, off, 64);
    if (lane == 0) s_red[wid] = sl;
    __syncthreads();
    float s = 0.f;
    #pragma unroll
    for (int w = 0; w < 8; ++w) s += s_red[qq * 8 + w];

    const float a = p * (1.0f / s);
    attn_out[(size_t)(bq0 + qq) * 512 + kk] = a;
    attnb[(size_t)(bq0 + qq) * 512 + kk] = (short)f2bf(a);
}

// ---------------------------------------------------------------------------
// PV GEMM: outh[b][128][1024] = attnb[b][128][512] @ valT[b][1024][512]^T
// 128m x 64n tile, K=512 (8 steps); grid b*16+nt = 64 blocks
__global__ __launch_bounds__(256) void pv_gemm(
    const short* __restrict__ attnb, const short* __restrict__ valT,
    float* __restrict__ outh)
{
    __shared__ short ldsA[2][128][64];
    __shared__ short ldsB[2][64][64];
    const int t = threadIdx.x, bx = blockIdx.x;
    const int b = bx >> 4, nt = bx & 15;
    const int n0 = nt * 64;
    const short* A = attnb + (size_t)b * 128 * 512;                    // [128][512]
    const short* B = valT + (size_t)b * 1024 * 512 + (size_t)n0 * 512; // [64][512] tile

    f32x4 acc[4][2];
    #pragma unroll
    for (int i = 0; i < 4; ++i)
        #pragma unroll
        for (int j = 0; j < 2; ++j) acc[i][j] = f32x4{0.f, 0.f, 0.f, 0.f};

    const int lane = t & 63, wid = t >> 6;
    const int wr = wid >> 1, wc = wid & 1;
    const int fr = lane & 15, fko = (lane >> 4) * 16;

    #define STAGE_PV(buf, k0) do {                                              \
        _Pragma("unroll")                                                       \
        for (int it = 0; it < 4; ++it) {                                        \
            const int idx = it * 256 + t;                                       \
            const int row = idx >> 3, c16 = idx & 7;                            \
            const int sc = c16 ^ (row & 7);                                     \
            GLD16(A + (size_t)row * 512 + (k0) + sc * 8,                        \
                  &ldsA[buf][0][0] + idx * 8);                                  \
        }                                                                       \
        _Pragma("unroll")                                                       \
        for (int it = 0; it < 2; ++it) {                                        \
            const int idx = it * 256 + t;                                       \
            const int row = idx >> 3, c16 = idx & 7;                            \
            const int sc = c16 ^ (row & 7);                                     \
            GLD16(B + (size_t)row * 512 + (k0) + sc * 8,                        \
                  &ldsB[buf][0][0] + idx * 8);                                  \
        }                                                                       \
    } while (0)

    #define COMPUTE_PV(buf) do {                                                \
        _Pragma("unroll")                                                       \
        for (int kk = 0; kk < 2; ++kk) {                                        \
            s16x8 af[4], bfv[2];                                                \
            _Pragma("unroll")                                                   \
            for (int i = 0; i < 4; ++i) {                                       \
                const int rowA = wr * 64 + i * 16 + fr;                         \
                int offA = rowA * 128 + kk * 64 + fko; offA ^= (rowA & 7) << 4; \
                af[i] = *(const s16x8*)((const char*)&ldsA[buf][0][0] + offA);  \
            }                                                                   \
            _Pragma("unroll")                                                   \
            for (int ni = 0; ni < 2; ++ni) {                                    \
                const int rowB = wc * 32 + ni * 16 + fr;                        \
                int offB = rowB * 128 + kk * 64 + fko; offB ^= (rowB & 7) << 4; \
                bfv[ni] = *(const s16x8*)((const char*)&ldsB[buf][0][0] + offB);\
            }                                                                   \
            _Pragma("unroll")                                                   \
            for (int mi = 0; mi < 4; ++mi)                                      \
                _Pragma("unroll")                                               \
                for (int ni = 0; ni < 2; ++ni)                                  \
                    acc[mi][ni] = __builtin_amdgcn_mfma_f32_16x16x32_bf16(      \
                                      af[mi], bfv[ni], acc[mi][ni], 0, 0, 0);   \
        }                                                                       \
    } while (0)

    STAGE_PV(0, 0);
    __syncthreads();
    int cur = 0;
    for (int s = 0; s < 7; ++s) {
        STAGE_PV(cur ^ 1, (s + 1) * 64);
        COMPUTE_PV(cur);
        __syncthreads();
        cur ^= 1;
    }
    COMPUTE_PV(cur);

    const int row0 = (lane >> 4) * 4;
    #pragma unroll
    for (int ni = 0; ni < 2; ++ni) {
        const int n = n0 + wc * 32 + ni * 16 + fr;
        #pragma unroll
        for (int mi = 0; mi < 4; ++mi) {
            const int m = wr * 64 + mi * 16 + row0;
            #pragma unroll
            for (int j = 0; j < 4; ++j)
                outh[(size_t)(b * 128 + m + j) * 1024 + n] = acc[mi][ni][j];
        }
    }
    #undef STAGE_PV
    #undef COMPUTE_PV
}

extern "C" void kernel_launch(void* const* d_in, const int* in_sizes, int n_in,
                              void* d_out, int out_size, void* d_ws, size_t ws_size,
                              hipStream_t stream)
{
    const float* query = (const float*)d_in[0];
    const float* key   = (const float*)d_in[1];
    const float* value = (const float*)d_in[2];
    const float* Wq    = (const float*)d_in[3];
    const float* bq    = (const float*)d_in[4];
    const float* Wk    = (const float*)d_in[5];
    const float* v     = (const float*)d_in[6];
    float* out = (float*)d_out;

    // workspace layout (20 MB):
    char* w = (char*)d_ws;
    float*          ws_Ea  = (float*)w;                       // 2 MB
    unsigned short* ws_EbT = (unsigned short*)(w + (2u << 20)); // 4 MB (bf16)
    short* Qb     = (short*)(w + (6u << 20));                 // 1 MB
    short* Kb     = (short*)(w + (7u << 20));                 // 4 MB
    short* WqT    = (short*)(w + (11u << 20));                // 2 MB
    short* WkT    = (short*)(w + (13u << 20));                // 2 MB
    short* valT   = (short*)(w + (15u << 20));                // 4 MB
    short* attnb  = (short*)(w + (19u << 20));                // 0.5 MB

    float* out_h    = out;                                // [512][1024]
    float* out_attn = out + (size_t)NB * NTQ * NH;        // [512][512]

    prep_kernel   <<<dim3(1664), dim3(256),  0, stream>>>(query, key, Wq, Wk, value,
                                                          Qb, Kb, WqT, WkT, valT);
    mm_kernel     <<<dim3(320),  dim3(256),  0, stream>>>(Qb, Kb, WqT, WkT, bq, ws_Ea, ws_EbT);
    scores_softmax<<<dim3(256),  dim3(1024), 0, stream>>>(ws_EbT, ws_Ea, v, out_attn, attnb);
    pv_gemm       <<<dim3(64),   dim3(256),  0, stream>>>(attnb, valT, out_h);
}